// Round 5
// baseline (4922.693 us; speedup 1.0000x reference)
//
#include <hip/hip_runtime.h>
#include <stdint.h>

// LEM recurrent net, MI355X persistent-kernel implementation, round 5.
// NGRP=4 batch groups (64 rows) x CBLK=48 column-blocks (16 cols) = 192
// blocks x 256 thr, 1 block/CU, weights pinned in LDS.
// State exchange: bf16, fragment-ordered layout [kt][rt][kg][r16][e].
// Stores: uncached write-through (sc0 sc1) -> MALL always fresh, no dirty
// L2 lines, no wbl2. Loads: CACHED (fill L1+XCD-L2) so the 48-way intra-
// group broadcast is served by L2; every wave issues buffer_inv sc0 sc1
// after each barrier-wait and before its own loads (per-wave program order
// => no stale line can be consumed, regardless of other waves/blocks).
// Group->XCD co-location (g=(bid%8)>>1) maximizes L2 reuse; correctness
// does not depend on the mapping. Barrier: 48 contiguous u32 flags per
// group-phase (plain uncached stores, no RMW), wave0 polls coalesced.

#define NINP 128
#define NHID 768
#define NOUT 128
#define T_STEPS 256
#define BATCH 256

#define NGRP 4
#define CBLK 48
#define NBLK (NGRP * CBLK)      // 192 blocks
#define NTHR 256
#define KH 24                   // K-chunks of 32 for K=768
#define KI 4                    // K-chunks for K=128

// LDS tile indices (tile = 16 cols x 32 k bf16 = 1KB, fragment-major)
#define T_INP0 72               // after 3*24 W_hid tiles
#define T_WZ0  88               // after 4*4 W_inp tiles
#define NTILES 112              // 112 KB LDS

// state layout [kt:24][rt:16][kg:4][r16:16][e:8] bf16; chunk stride (bf16):
#define CHS 8192                // 16*4*16*8
#define SBUF 196608             // bf16 elements per state buffer (384KB)

typedef short bf16x8 __attribute__((ext_vector_type(8)));
typedef float f32x4 __attribute__((ext_vector_type(4)));
typedef unsigned uint32x4 __attribute__((ext_vector_type(4)));

__device__ __forceinline__ unsigned short f2b(float f) {
  union { float f; unsigned u; } x; x.f = f;
  return (unsigned short)((x.u + 0x7fffu + ((x.u >> 16) & 1u)) >> 16);  // RNE
}
__device__ __forceinline__ float b2f(unsigned short h) {
  union { unsigned u; float f; } x; x.u = ((unsigned)h) << 16; return x.f;
}
__device__ __forceinline__ float fsig(float x) { return 1.0f / (1.0f + __expf(-x)); }
__device__ __forceinline__ float ftanh(float x) {
  float e = __expf(2.0f * x);
  return 1.0f - 2.0f / (e + 1.0f);
}

#define MFMA16(a, b, c) __builtin_amdgcn_mfma_f32_16x16x32_bf16(a, b, c, 0, 0, 0)

#define AL32(p) __hip_atomic_load((const unsigned*)(p), __ATOMIC_RELAXED, __HIP_MEMORY_SCOPE_AGENT)
#define AS32(p, v) __hip_atomic_store((unsigned*)(p), (v), __ATOMIC_RELAXED, __HIP_MEMORY_SCOPE_AGENT)
#define AS16(p, v) __hip_atomic_store((unsigned short*)(p), (v), __ATOMIC_RELAXED, __HIP_MEMORY_SCOPE_AGENT)

// CACHED 16B load (fills L1 + XCD L2); valid only after s_waitcnt
__device__ __forceinline__ void cld16(uint32x4* dst, const unsigned short* addr) {
  asm volatile("global_load_dwordx4 %0, %1, off"
               : "=v"(*dst) : "v"(addr));
}
#define WAITV(N) do { \
  asm volatile("s_waitcnt vmcnt(" #N ")" ::: "memory"); \
  __builtin_amdgcn_sched_barrier(0); } while (0)

// invalidate this CU's vector L1 + this XCD's L2 (no writeback needed:
// state stores are write-through). Each wave issues it before its loads.
__device__ __forceinline__ void cache_inv() {
  asm volatile("buffer_inv sc0 sc1" ::: "memory");
  __builtin_amdgcn_sched_barrier(0);
}

// fp32 -> hi/lo bf16 fragments (x input, W_cls)
__device__ __forceinline__ void split8(const float* p, bf16x8* hi, bf16x8* lo) {
  union { bf16x8 v; unsigned short s[8]; } H, L;
#pragma unroll
  for (int e = 0; e < 8; ++e) {
    float v = p[e];
    unsigned short h = f2b(v);
    H.s[e] = h;
    L.s[e] = f2b(v - b2f(h));
  }
  *hi = H.v; *lo = L.v;
}

__global__ __launch_bounds__(NTHR, 1) void lem_kernel(
    const float* __restrict__ x,       // [T][B][NINP]
    const float* __restrict__ W_inp,   // [4*NHID][NINP]
    const float* __restrict__ b_inp,   // [4*NHID]
    const float* __restrict__ W_hid,   // [3*NHID][NHID]
    const float* __restrict__ b_hid,   // [3*NHID]
    const float* __restrict__ W_z,     // [NHID][NHID]
    const float* __restrict__ b_z,     // [NHID]
    const float* __restrict__ W_cls,   // [NOUT][NHID]
    const float* __restrict__ b_cls,   // [NOUT]
    float* __restrict__ out,           // [B][NOUT]
    unsigned short* __restrict__ Y,    // bf16 state, fragment-ordered
    unsigned short* __restrict__ Z,
    unsigned* __restrict__ flags)      // per group: flagA[48], pad, flagB[48]
{
  __shared__ unsigned short wlds[NTILES * 512];  // 112 KB

  const int tid = threadIdx.x;
  const int l   = tid & 63;
  const int w   = tid >> 6;            // wave 0..3
  const int bid = blockIdx.x;
  // XCD-aware: XCD = bid%8 (round-robin heuristic); same group on same XCD
  const int g   = (bid & 7) >> 1;
  const int c   = (bid >> 3) * 2 + (bid & 1);
  const int colbase = c * 16;
  const int lc  = l & 15;
  const int kg8 = (l >> 4) * 8;

  // ---- one-time: pack weight slices into LDS (bf16, fragment-major) ----
  for (int idx = tid; idx < NTILES * 512; idx += NTHR) {
    int t = idx >> 9;
    int r = idx & 511;
    int ll = r >> 3;
    int e  = r & 7;
    int col16 = ll & 15;
    int kk = ((ll >> 4) * 8) + e;
    float v;
    if (t < T_INP0) {                      // W_hid
      int seg = t / 24, kt = t % 24;
      v = W_hid[(size_t)(seg * NHID + colbase + col16) * NHID + kt * 32 + kk];
    } else if (t < T_WZ0) {                // W_inp
      int u = t - T_INP0; int seg = u >> 2, kt = u & 3;
      v = W_inp[(size_t)(seg * NHID + colbase + col16) * NINP + kt * 32 + kk];
    } else {                               // W_z
      int kt = t - T_WZ0;
      v = W_z[(size_t)(colbase + col16) * NHID + kt * 32 + kk];
    }
    wlds[idx] = f2b(v);
  }
  __syncthreads();

#define LDSB(t) (*(const bf16x8*)&wlds[((t) << 9) + (l << 3)])

  const int col  = colbase + lc;
  const int rt   = 4 * g + w;                   // row tile (16 rows)
  const int rowA = rt * 16 + lc;                // A-fragment row
  const int rowD = rt * 16 + (l >> 4) * 4;      // D rows rowD..rowD+3
  const int rtl  = rt * 512 + (l >> 4) * 128 + lc * 8;  // per-lane load base
  const float c1 = b_inp[col] + b_hid[col];
  const float c2 = b_inp[NHID + col] + b_hid[NHID + col];
  const float cy = b_inp[3 * NHID + col] + b_hid[2 * NHID + col];
  const float cz = b_inp[2 * NHID + col] + b_z[col];
  // store addressing (fragment-ordered, bf16 units)
  const int kts = col >> 5, kgs = (col >> 3) & 3, es = col & 7;
  const int r16b = (l >> 4) * 4;
  unsigned short* zs = Z + ((kts * 16 + rt) * 4 + kgs) * 128 + es;
  unsigned short* ys = Y + ((kts * 16 + rt) * 4 + kgs) * 128 + es;
  unsigned* gfA = flags + g * 128;
  unsigned* gfB = gfA + 64;

  // kill any stale state lines from a previous replay of this kernel
  cache_inv();

  // input projection for step 0 (cached loads; x is read-only)
  f32x4 ai0{0,0,0,0}, ai1{0,0,0,0}, ai2{0,0,0,0}, ai3{0,0,0,0};
  {
    const float* xp0 = x + (size_t)rowA * NINP;
#pragma unroll
    for (int kt = 0; kt < KI; ++kt) {
      bf16x8 ah, al;
      split8(xp0 + kt * 32 + kg8, &ah, &al);
      ai0 = MFMA16(ah, LDSB(T_INP0 + 0 * 4 + kt), ai0);
      ai0 = MFMA16(al, LDSB(T_INP0 + 0 * 4 + kt), ai0);
      ai1 = MFMA16(ah, LDSB(T_INP0 + 1 * 4 + kt), ai1);
      ai1 = MFMA16(al, LDSB(T_INP0 + 1 * 4 + kt), ai1);
      ai2 = MFMA16(ah, LDSB(T_INP0 + 2 * 4 + kt), ai2);
      ai2 = MFMA16(al, LDSB(T_INP0 + 2 * 4 + kt), ai2);
      ai3 = MFMA16(ah, LDSB(T_INP0 + 3 * 4 + kt), ai3);
      ai3 = MFMA16(al, LDSB(T_INP0 + 3 * 4 + kt), ai3);
    }
  }

  f32x4 yloc{0,0,0,0}, zloc{0,0,0,0}, msb{0,0,0,0};

  // 6-deep pipelined slab read: 12 batches x 2 chunks x 1 dwordx4
#define ISSUE(slot, jj) do { \
    cld16(&bufs[slot][0], pbase + (2 * (jj)) * CHS); \
    cld16(&bufs[slot][1], pbase + (2 * (jj) + 1) * CHS); } while (0)

  for (int s = 0; s < T_STEPS; ++s) {
    // ---------- phase A: hid = y @ W_hid^T, z update ----------
    f32x4 h0{0,0,0,0}, h1{0,0,0,0}, h2{0,0,0,0};
    {
      const unsigned short* pbase = Y + rtl;
      uint32x4 bufs[6][2];
      ISSUE(0, 0); ISSUE(1, 1); ISSUE(2, 2); ISSUE(3, 3); ISSUE(4, 4);
#pragma unroll
      for (int j = 0; j < 12; ++j) {
        if (j <= 6) { ISSUE((j + 5) % 6, j + 5); WAITV(10); }
        else if (j == 7) { WAITV(8); }
        else if (j == 8) { WAITV(6); }
        else if (j == 9) { WAITV(4); }
        else if (j == 10) { WAITV(2); }
        else { WAITV(0); }
        const int sl = j % 6;
        bf16x8 a0 = __builtin_bit_cast(bf16x8, bufs[sl][0]);
        h0 = MFMA16(a0, LDSB(0 * 24 + 2 * j), h0);
        h1 = MFMA16(a0, LDSB(1 * 24 + 2 * j), h1);
        h2 = MFMA16(a0, LDSB(2 * 24 + 2 * j), h2);
        bf16x8 a1 = __builtin_bit_cast(bf16x8, bufs[sl][1]);
        h0 = MFMA16(a1, LDSB(0 * 24 + 2 * j + 1), h0);
        h1 = MFMA16(a1, LDSB(1 * 24 + 2 * j + 1), h1);
        h2 = MFMA16(a1, LDSB(2 * 24 + 2 * j + 1), h2);
      }
    }
#pragma unroll
    for (int i = 0; i < 4; ++i) {
      float a1 = fsig(ai0[i] + h0[i] + c1);          // ms_dt_bar
      float a2 = fsig(ai1[i] + h1[i] + c2);          // ms_dt
      float gg = ftanh(ai3[i] + h2[i] + cy);
      float zn = (1.0f - a2) * zloc[i] + a2 * gg;
      zloc[i] = zn;
      msb[i] = a1;
      AS16(zs + (r16b + i) * 8, f2b(zn));            // uncached write-through
    }
    __syncthreads();                       // drains vmcnt: stores at MALL
    if (tid == 0) AS32(&gfA[c], (unsigned)(s + 1));

    // overlap barrier latency: input projection for step s+1 (cached)
    f32x4 ni0{0,0,0,0}, ni1{0,0,0,0}, ni2{0,0,0,0}, ni3{0,0,0,0};
    if (s + 1 < T_STEPS) {
      const float* xp = x + ((size_t)(s + 1) * BATCH + rowA) * NINP;
#pragma unroll
      for (int kt = 0; kt < KI; ++kt) {
        bf16x8 ah, al;
        split8(xp + kt * 32 + kg8, &ah, &al);
        ni0 = MFMA16(ah, LDSB(T_INP0 + 0 * 4 + kt), ni0);
        ni0 = MFMA16(al, LDSB(T_INP0 + 0 * 4 + kt), ni0);
        ni1 = MFMA16(ah, LDSB(T_INP0 + 1 * 4 + kt), ni1);
        ni1 = MFMA16(al, LDSB(T_INP0 + 1 * 4 + kt), ni1);
        ni2 = MFMA16(ah, LDSB(T_INP0 + 2 * 4 + kt), ni2);
        ni2 = MFMA16(al, LDSB(T_INP0 + 2 * 4 + kt), ni2);
        ni3 = MFMA16(ah, LDSB(T_INP0 + 3 * 4 + kt), ni3);
        ni3 = MFMA16(al, LDSB(T_INP0 + 3 * 4 + kt), ni3);
      }
    }
    // wait A: all 48 flagA >= s+1 (uncached flag reads)
    if (w == 0) {
      const unsigned* fp = gfA + (l < CBLK ? l : 0);
      while (true) {
        unsigned v = AL32(fp);
        if (__all((l >= CBLK) || (v >= (unsigned)(s + 1)))) break;
        __builtin_amdgcn_s_sleep(1);
      }
    }
    __syncthreads();
    cache_inv();   // every wave: own L1/L2 inv precedes its own Z loads

    // ---------- phase B: zWz = z @ W_z^T, y update ----------
    f32x4 az0{0,0,0,0}, az1{0,0,0,0};
    {
      const unsigned short* pbase = Z + rtl;
      uint32x4 bufs[6][2];
      ISSUE(0, 0); ISSUE(1, 1); ISSUE(2, 2); ISSUE(3, 3); ISSUE(4, 4);
#pragma unroll
      for (int j = 0; j < 12; ++j) {
        if (j <= 6) { ISSUE((j + 5) % 6, j + 5); WAITV(10); }
        else if (j == 7) { WAITV(8); }
        else if (j == 8) { WAITV(6); }
        else if (j == 9) { WAITV(4); }
        else if (j == 10) { WAITV(2); }
        else { WAITV(0); }
        const int sl = j % 6;
        bf16x8 a0 = __builtin_bit_cast(bf16x8, bufs[sl][0]);
        az0 = MFMA16(a0, LDSB(T_WZ0 + 2 * j), az0);
        bf16x8 a1 = __builtin_bit_cast(bf16x8, bufs[sl][1]);
        az1 = MFMA16(a1, LDSB(T_WZ0 + 2 * j + 1), az1);
      }
    }
#pragma unroll
    for (int i = 0; i < 4; ++i) {
      float tt = ftanh(az0[i] + az1[i] + ai2[i] + cz);
      float yn = (1.0f - msb[i]) * yloc[i] + msb[i] * tt;
      yloc[i] = yn;
      AS16(ys + (r16b + i) * 8, f2b(yn));
    }
    __syncthreads();
    if (tid == 0) AS32(&gfB[c], (unsigned)(s + 1));
    if (w == 0) {
      const unsigned* fp = gfB + (l < CBLK ? l : 0);
      while (true) {
        unsigned v = AL32(fp);
        if (__all((l >= CBLK) || (v >= (unsigned)(s + 1)))) break;
        __builtin_amdgcn_s_sleep(1);
      }
    }
    __syncthreads();
    cache_inv();   // before next phase A's Y loads (and epilogue's)

    ai0 = ni0; ai1 = ni1; ai2 = ni2; ai3 = ni3;
  }

  // ---------- epilogue: out = y @ W_cls^T + b_cls (blocks c<8) ----------
  if (c < 8) {
    f32x4 ao0{0,0,0,0}, ao1{0,0,0,0};
    const unsigned short* pbase = Y + rtl;
    for (int kt = 0; kt < KH; kt += 2) {
      uint32x4 q0, q1;
      cld16(&q0, pbase + kt * CHS);
      cld16(&q1, pbase + (kt + 1) * CHS);
      bf16x8 bh0, bl0, bh1, bl1;
      split8(W_cls + (size_t)(colbase + lc) * NHID + kt * 32 + kg8, &bh0, &bl0);
      split8(W_cls + (size_t)(colbase + lc) * NHID + (kt + 1) * 32 + kg8, &bh1, &bl1);
      WAITV(0);
      bf16x8 a0 = __builtin_bit_cast(bf16x8, q0);
      ao0 = MFMA16(a0, bh0, ao0); ao0 = MFMA16(a0, bl0, ao0);
      bf16x8 a1 = __builtin_bit_cast(bf16x8, q1);
      ao1 = MFMA16(a1, bh1, ao1); ao1 = MFMA16(a1, bl1, ao1);
    }
    float bc = b_cls[colbase + lc];
#pragma unroll
    for (int i = 0; i < 4; ++i)
      out[(size_t)(rowD + i) * NOUT + colbase + lc] = ao0[i] + ao1[i] + bc;
  }
}

extern "C" void kernel_launch(void* const* d_in, const int* in_sizes, int n_in,
                              void* d_out, int out_size, void* d_ws, size_t ws_size,
                              hipStream_t stream) {
  (void)in_sizes; (void)n_in; (void)out_size; (void)ws_size;
  const float* x     = (const float*)d_in[0];
  const float* W_inp = (const float*)d_in[1];
  const float* b_inp = (const float*)d_in[2];
  const float* W_hid = (const float*)d_in[3];
  const float* b_hid = (const float*)d_in[4];
  const float* W_z   = (const float*)d_in[5];
  const float* b_z   = (const float*)d_in[6];
  const float* W_cls = (const float*)d_in[7];
  const float* b_cls = (const float*)d_in[8];

  // workspace: Y (384KB), Z (384KB), flags (4 groups * 128 u32 = 2KB)
  unsigned short* Y = (unsigned short*)d_ws;
  unsigned short* Z = Y + SBUF;
  unsigned* flags = (unsigned*)((char*)d_ws + 2 * SBUF * sizeof(unsigned short));

  hipMemsetAsync(d_ws, 0, 2 * SBUF * sizeof(unsigned short) + NGRP * 128 * sizeof(unsigned), stream);

  lem_kernel<<<dim3(NBLK), dim3(NTHR), 0, stream>>>(
      x, W_inp, b_inp, W_hid, b_hid, W_z, b_z, W_cls, b_cls,
      (float*)d_out, Y, Z, flags);
}

// Round 6
// 4204.309 us; speedup vs baseline: 1.1709x; 1.1709x over previous
//
#include <hip/hip_runtime.h>
#include <stdint.h>

// LEM recurrent net, MI355X persistent-kernel implementation, round 6.
// NGRP=4 batch groups (64 rows) x CBLK=24 column-blocks (32 cols) = 96
// blocks x 256 thr, 1 block/CU. W_hid (144KB) pinned in LDS; W_z/W_inp
// streamed as pre-converted bf16 fragment tiles (read-only -> L1/L2 cached;
// same-c blocks co-located per XCD by default bid mapping).
// State exchange: bf16, fragment-ordered [kt][rt][kg][r16][e]; uncached
// (sc0 sc1) dwordx4 loads, 6-batch counted-vmcnt pipeline (W_z frags join
// the same counted batches). Barrier: 24 contiguous u32 flags per
// group-phase, plain stores, wave0 polls coalesced. No wbl2/inv.

#define NINP 128
#define NHID 768
#define NOUT 128
#define T_STEPS 256
#define BATCH 256

#define NGRP 4
#define CBLK 24
#define NBLK (NGRP * CBLK)      // 96 blocks
#define NTHR 256
#define KH 24                   // K-chunks of 32 for K=768
#define KI 4                    // K-chunks for K=128

#define NHTILES 144             // W_hid LDS tiles: (seg:3 x n2:2 x kt:24)

// state layout [kt:24][rt:16][kg:4][r16:16][e:8] bf16; chunk stride (bf16):
#define CHS 8192                // 16*4*16*8
#define SBUF 196608             // bf16 elements per state buffer (384KB)

#define WZ_TILES 1152           // (c:24 x n2:2 x kt:24)
#define WI_TILES 768            // (c:24 x seg:4 x n2:2 x kt:4)

typedef short bf16x8 __attribute__((ext_vector_type(8)));
typedef float f32x4 __attribute__((ext_vector_type(4)));
typedef unsigned uint32x4 __attribute__((ext_vector_type(4)));

__device__ __forceinline__ unsigned short f2b(float f) {
  union { float f; unsigned u; } x; x.f = f;
  return (unsigned short)((x.u + 0x7fffu + ((x.u >> 16) & 1u)) >> 16);  // RNE
}
__device__ __forceinline__ float b2f(unsigned short h) {
  union { unsigned u; float f; } x; x.u = ((unsigned)h) << 16; return x.f;
}
__device__ __forceinline__ float fsig(float x) { return 1.0f / (1.0f + __expf(-x)); }
__device__ __forceinline__ float ftanh(float x) {
  float e = __expf(2.0f * x);
  return 1.0f - 2.0f / (e + 1.0f);
}

#define MFMA16(a, b, c) __builtin_amdgcn_mfma_f32_16x16x32_bf16(a, b, c, 0, 0, 0)

#define AL32(p) __hip_atomic_load((const unsigned*)(p), __ATOMIC_RELAXED, __HIP_MEMORY_SCOPE_AGENT)
#define AS32(p, v) __hip_atomic_store((unsigned*)(p), (v), __ATOMIC_RELAXED, __HIP_MEMORY_SCOPE_AGENT)
#define AS16(p, v) __hip_atomic_store((unsigned short*)(p), (v), __ATOMIC_RELAXED, __HIP_MEMORY_SCOPE_AGENT)

// uncached (device-coherent) 16B load; valid only after s_waitcnt
__device__ __forceinline__ void uld16(uint32x4* dst, const unsigned short* addr) {
  asm volatile("global_load_dwordx4 %0, %1, off sc0 sc1"
               : "=v"(*dst) : "v"(addr));
}
// cached 16B load into bf16x8 (read-only weight frags), manually counted
__device__ __forceinline__ void cld16b(bf16x8* dst, const unsigned short* addr) {
  asm volatile("global_load_dwordx4 %0, %1, off"
               : "=v"(*dst) : "v"(addr));
}
#define WAITV(N) do { \
  asm volatile("s_waitcnt vmcnt(" #N ")" ::: "memory"); \
  __builtin_amdgcn_sched_barrier(0); } while (0)

// fp32 -> hi/lo bf16 fragments (x input, W_cls)
__device__ __forceinline__ void split8(const float* p, bf16x8* hi, bf16x8* lo) {
  union { bf16x8 v; unsigned short s[8]; } H, L;
#pragma unroll
  for (int e = 0; e < 8; ++e) {
    float v = p[e];
    unsigned short h = f2b(v);
    H.s[e] = h;
    L.s[e] = f2b(v - b2f(h));
  }
  *hi = H.v; *lo = L.v;
}

// ---- init kernel: convert W_z / W_inp to bf16 fragment tiles ----
__global__ __launch_bounds__(256) void conv_w(
    const float* __restrict__ W_z, const float* __restrict__ W_inp,
    unsigned short* __restrict__ Wz, unsigned short* __restrict__ Wi) {
  int idx = blockIdx.x * 256 + threadIdx.x;   // (1152+768)*512 total
  int t = idx >> 9, r = idx & 511;
  int ll = r >> 3, e = r & 7;
  int col16 = ll & 15;
  int kk = ((ll >> 4) * 8) + e;
  if (t < WZ_TILES) {                // tile = (c*2+n2)*24 + kt
    int kt = t % 24, n2 = (t / 24) & 1, c = t / 48;
    Wz[idx] = f2b(W_z[(size_t)(c * 32 + n2 * 16 + col16) * NHID + kt * 32 + kk]);
  } else {                           // tile = ((c*4+seg)*2+n2)*4 + kt
    int u = t - WZ_TILES;
    int kt = u & 3, n2 = (u >> 2) & 1, seg = (u >> 3) & 3, c = u >> 5;
    Wi[(size_t)u * 512 + r] =
        f2b(W_inp[(size_t)(seg * NHID + c * 32 + n2 * 16 + col16) * NINP + kt * 32 + kk]);
  }
}

__global__ __launch_bounds__(NTHR, 1) void lem_kernel(
    const float* __restrict__ x,       // [T][B][NINP]
    const float* __restrict__ b_inp,   // [4*NHID]
    const float* __restrict__ W_hid,   // [3*NHID][NHID]
    const float* __restrict__ b_hid,   // [3*NHID]
    const float* __restrict__ b_z,     // [NHID]
    const float* __restrict__ W_cls,   // [NOUT][NHID]
    const float* __restrict__ b_cls,   // [NOUT]
    float* __restrict__ out,           // [B][NOUT]
    unsigned short* __restrict__ Y,    // bf16 state, fragment-ordered
    unsigned short* __restrict__ Z,
    unsigned* __restrict__ flags,      // per group: flagA[24] @0, flagB[24] @64
    const unsigned short* __restrict__ Wz,   // bf16 W_z tiles
    const unsigned short* __restrict__ Wi)   // bf16 W_inp tiles
{
  __shared__ unsigned short wlds[NHTILES * 512];  // 144 KB

  const int tid = threadIdx.x;
  const int l   = tid & 63;
  const int w   = tid >> 6;            // wave 0..3
  const int g   = blockIdx.x / CBLK;   // bid%CBLK = c -> XCD = c%8 (co-located)
  const int c   = blockIdx.x % CBLK;
  const int colbase = c * 32;
  const int lc  = l & 15;
  const int kg8 = (l >> 4) * 8;

  // ---- one-time: pack W_hid slice into LDS (bf16, fragment-major) ----
  for (int idx = tid; idx < NHTILES * 512; idx += NTHR) {
    int t = idx >> 9;                  // (seg*2+n2)*24 + kt
    int r = idx & 511;
    int ll = r >> 3, e = r & 7;
    int col16 = ll & 15;
    int kk = ((ll >> 4) * 8) + e;
    int kt = t % 24, sn = t / 24;
    int seg = sn >> 1, n2 = sn & 1;
    wlds[idx] = f2b(W_hid[(size_t)(seg * NHID + colbase + n2 * 16 + col16) * NHID + kt * 32 + kk]);
  }
  __syncthreads();

#define LDSB(t) (*(const bf16x8*)&wlds[((t) << 9) + (l << 3)])

  const int rt   = 4 * g + w;                   // row tile (16 rows)
  const int rowA = rt * 16 + lc;                // A-fragment row
  const int rowD = rt * 16 + (l >> 4) * 4;      // D rows rowD..rowD+3
  const int rtl  = rt * 512 + (l >> 4) * 128 + lc * 8;  // per-lane load base
  const int r16b = (l >> 4) * 4;

  // per-lane biases / store pointers for both 16-col tiles (n2 = 0,1)
  float c1[2], c2[2], cy[2], cz[2];
  unsigned short *zs[2], *ys[2];
#pragma unroll
  for (int n2 = 0; n2 < 2; ++n2) {
    int col = colbase + n2 * 16 + lc;
    c1[n2] = b_inp[col] + b_hid[col];
    c2[n2] = b_inp[NHID + col] + b_hid[NHID + col];
    cy[n2] = b_inp[3 * NHID + col] + b_hid[2 * NHID + col];
    cz[n2] = b_inp[2 * NHID + col] + b_z[col];
    int kts = col >> 5, kgs = (col >> 3) & 3, es = col & 7;
    zs[n2] = Z + ((kts * 16 + rt) * 4 + kgs) * 128 + es;
    ys[n2] = Y + ((kts * 16 + rt) * 4 + kgs) * 128 + es;
  }
  unsigned* gfA = flags + g * 128;
  unsigned* gfB = gfA + 64;
  const unsigned short* wzb = Wz + (size_t)(c * 48) * 512 + l * 8;  // (n2*24+kt)*512
  const unsigned short* wib = Wi + (size_t)(c * 32) * 512 + l * 8;  // ((seg*2+n2)*4+kt)*512

  // input projection for step 0 (cached loads; read-only data)
  f32x4 ai[4][2];
#pragma unroll
  for (int sg = 0; sg < 4; ++sg)
#pragma unroll
    for (int n2 = 0; n2 < 2; ++n2) ai[sg][n2] = f32x4{0, 0, 0, 0};
  {
    const float* xp0 = x + (size_t)rowA * NINP;
#pragma unroll
    for (int kt = 0; kt < KI; ++kt) {
      bf16x8 ah, al;
      split8(xp0 + kt * 32 + kg8, &ah, &al);
#pragma unroll
      for (int sg = 0; sg < 4; ++sg)
#pragma unroll
        for (int n2 = 0; n2 < 2; ++n2) {
          bf16x8 bb = *(const bf16x8*)(wib + (((sg * 2 + n2) * 4) + kt) * 512);
          ai[sg][n2] = MFMA16(ah, bb, ai[sg][n2]);
          ai[sg][n2] = MFMA16(al, bb, ai[sg][n2]);
        }
    }
  }

  f32x4 yloc[2], zloc[2], msb[2];
#pragma unroll
  for (int n2 = 0; n2 < 2; ++n2) {
    yloc[n2] = f32x4{0, 0, 0, 0};
    zloc[n2] = f32x4{0, 0, 0, 0};
  }

#define ISSUE_A(slot, jj) do { \
    uld16(&bufs[slot][0], pbase + (2 * (jj)) * CHS); \
    uld16(&bufs[slot][1], pbase + (2 * (jj) + 1) * CHS); } while (0)

#define ISSUE_B(slot, jj) do { \
    uld16(&bufs[slot][0], pbase + (2 * (jj)) * CHS); \
    uld16(&bufs[slot][1], pbase + (2 * (jj) + 1) * CHS); \
    cld16b(&wzf[slot][0], wzb + (0 * 24 + 2 * (jj)) * 512); \
    cld16b(&wzf[slot][1], wzb + (1 * 24 + 2 * (jj)) * 512); \
    cld16b(&wzf[slot][2], wzb + (0 * 24 + 2 * (jj) + 1) * 512); \
    cld16b(&wzf[slot][3], wzb + (1 * 24 + 2 * (jj) + 1) * 512); } while (0)

  for (int s = 0; s < T_STEPS; ++s) {
    // ---------- phase A: hid = y @ W_hid^T, z update ----------
    f32x4 h[3][2];
#pragma unroll
    for (int sg = 0; sg < 3; ++sg)
#pragma unroll
      for (int n2 = 0; n2 < 2; ++n2) h[sg][n2] = f32x4{0, 0, 0, 0};
    {
      const unsigned short* pbase = Y + rtl;
      uint32x4 bufs[6][2];
      ISSUE_A(0, 0); ISSUE_A(1, 1); ISSUE_A(2, 2); ISSUE_A(3, 3); ISSUE_A(4, 4);
#pragma unroll
      for (int j = 0; j < 12; ++j) {
        if (j <= 6) { ISSUE_A((j + 5) % 6, j + 5); WAITV(10); }
        else if (j == 7) { WAITV(8); }
        else if (j == 8) { WAITV(6); }
        else if (j == 9) { WAITV(4); }
        else if (j == 10) { WAITV(2); }
        else { WAITV(0); }
        const int sl = j % 6;
        bf16x8 a0 = __builtin_bit_cast(bf16x8, bufs[sl][0]);
#pragma unroll
        for (int sg = 0; sg < 3; ++sg)
#pragma unroll
          for (int n2 = 0; n2 < 2; ++n2)
            h[sg][n2] = MFMA16(a0, LDSB((sg * 2 + n2) * 24 + 2 * j), h[sg][n2]);
        bf16x8 a1 = __builtin_bit_cast(bf16x8, bufs[sl][1]);
#pragma unroll
        for (int sg = 0; sg < 3; ++sg)
#pragma unroll
          for (int n2 = 0; n2 < 2; ++n2)
            h[sg][n2] = MFMA16(a1, LDSB((sg * 2 + n2) * 24 + 2 * j + 1), h[sg][n2]);
      }
    }
#pragma unroll
    for (int n2 = 0; n2 < 2; ++n2)
#pragma unroll
      for (int i = 0; i < 4; ++i) {
        float a1 = fsig(ai[0][n2][i] + h[0][n2][i] + c1[n2]);   // ms_dt_bar
        float a2 = fsig(ai[1][n2][i] + h[1][n2][i] + c2[n2]);   // ms_dt
        float gg = ftanh(ai[3][n2][i] + h[2][n2][i] + cy[n2]);
        float zn = (1.0f - a2) * zloc[n2][i] + a2 * gg;
        zloc[n2][i] = zn;
        msb[n2][i] = a1;
        AS16(zs[n2] + (r16b + i) * 8, f2b(zn));   // uncached write-through
      }
    __syncthreads();                       // drains vmcnt: stores at MALL
    if (tid == 0) AS32(&gfA[c], (unsigned)(s + 1));

    // overlap barrier latency: input projection for step s+1 (cached)
    f32x4 ni[4][2];
#pragma unroll
    for (int sg = 0; sg < 4; ++sg)
#pragma unroll
      for (int n2 = 0; n2 < 2; ++n2) ni[sg][n2] = f32x4{0, 0, 0, 0};
    if (s + 1 < T_STEPS) {
      const float* xp = x + ((size_t)(s + 1) * BATCH + rowA) * NINP;
#pragma unroll
      for (int kt = 0; kt < KI; ++kt) {
        bf16x8 ah, al;
        split8(xp + kt * 32 + kg8, &ah, &al);
#pragma unroll
        for (int sg = 0; sg < 4; ++sg)
#pragma unroll
          for (int n2 = 0; n2 < 2; ++n2) {
            bf16x8 bb = *(const bf16x8*)(wib + (((sg * 2 + n2) * 4) + kt) * 512);
            ni[sg][n2] = MFMA16(ah, bb, ni[sg][n2]);
            ni[sg][n2] = MFMA16(al, bb, ni[sg][n2]);
          }
      }
    }
    // wait A: all 24 flagA >= s+1 (coalesced 96B poll)
    if (w == 0) {
      const unsigned* fp = gfA + (l < CBLK ? l : 0);
      while (true) {
        unsigned v = AL32(fp);
        if (__all((l >= CBLK) || (v >= (unsigned)(s + 1)))) break;
        __builtin_amdgcn_s_sleep(1);
      }
    }
    __syncthreads();

    // ---------- phase B: zWz = z @ W_z^T, y update ----------
    f32x4 az[2];
    az[0] = f32x4{0, 0, 0, 0}; az[1] = f32x4{0, 0, 0, 0};
    {
      const unsigned short* pbase = Z + rtl;
      uint32x4 bufs[6][2];
      bf16x8 wzf[6][4];
      ISSUE_B(0, 0); ISSUE_B(1, 1); ISSUE_B(2, 2); ISSUE_B(3, 3); ISSUE_B(4, 4);
#pragma unroll
      for (int j = 0; j < 12; ++j) {
        if (j <= 6) { ISSUE_B((j + 5) % 6, j + 5); WAITV(30); }
        else if (j == 7) { WAITV(24); }
        else if (j == 8) { WAITV(18); }
        else if (j == 9) { WAITV(12); }
        else if (j == 10) { WAITV(6); }
        else { WAITV(0); }
        const int sl = j % 6;
        bf16x8 a0 = __builtin_bit_cast(bf16x8, bufs[sl][0]);
        az[0] = MFMA16(a0, wzf[sl][0], az[0]);
        az[1] = MFMA16(a0, wzf[sl][1], az[1]);
        bf16x8 a1 = __builtin_bit_cast(bf16x8, bufs[sl][1]);
        az[0] = MFMA16(a1, wzf[sl][2], az[0]);
        az[1] = MFMA16(a1, wzf[sl][3], az[1]);
      }
    }
#pragma unroll
    for (int n2 = 0; n2 < 2; ++n2)
#pragma unroll
      for (int i = 0; i < 4; ++i) {
        float tt = ftanh(az[n2][i] + ai[2][n2][i] + cz[n2]);
        float yn = (1.0f - msb[n2][i]) * yloc[n2][i] + msb[n2][i] * tt;
        yloc[n2][i] = yn;
        AS16(ys[n2] + (r16b + i) * 8, f2b(yn));
      }
    __syncthreads();
    if (tid == 0) AS32(&gfB[c], (unsigned)(s + 1));
    if (w == 0) {
      const unsigned* fp = gfB + (l < CBLK ? l : 0);
      while (true) {
        unsigned v = AL32(fp);
        if (__all((l >= CBLK) || (v >= (unsigned)(s + 1)))) break;
        __builtin_amdgcn_s_sleep(1);
      }
    }
    __syncthreads();

#pragma unroll
    for (int sg = 0; sg < 4; ++sg)
#pragma unroll
      for (int n2 = 0; n2 < 2; ++n2) ai[sg][n2] = ni[sg][n2];
  }

  // ---------- epilogue: out = y @ W_cls^T + b_cls (blocks c<4) ----------
  if (c < 4) {
    f32x4 ao[2];
    ao[0] = f32x4{0, 0, 0, 0}; ao[1] = f32x4{0, 0, 0, 0};
    const unsigned short* pbase = Y + rtl;
    for (int kt = 0; kt < KH; ++kt) {
      uint32x4 q;
      uld16(&q, pbase + kt * CHS);
      bf16x8 bh0, bl0, bh1, bl1;
      split8(W_cls + (size_t)(colbase + lc) * NHID + kt * 32 + kg8, &bh0, &bl0);
      split8(W_cls + (size_t)(colbase + 16 + lc) * NHID + kt * 32 + kg8, &bh1, &bl1);
      WAITV(0);
      bf16x8 a = __builtin_bit_cast(bf16x8, q);
      ao[0] = MFMA16(a, bh0, ao[0]); ao[0] = MFMA16(a, bl0, ao[0]);
      ao[1] = MFMA16(a, bh1, ao[1]); ao[1] = MFMA16(a, bl1, ao[1]);
    }
#pragma unroll
    for (int n2 = 0; n2 < 2; ++n2) {
      float bc = b_cls[colbase + n2 * 16 + lc];
#pragma unroll
      for (int i = 0; i < 4; ++i)
        out[(size_t)(rowD + i) * NOUT + colbase + n2 * 16 + lc] = ao[n2][i] + bc;
    }
  }
}

extern "C" void kernel_launch(void* const* d_in, const int* in_sizes, int n_in,
                              void* d_out, int out_size, void* d_ws, size_t ws_size,
                              hipStream_t stream) {
  (void)in_sizes; (void)n_in; (void)out_size; (void)ws_size;
  const float* x     = (const float*)d_in[0];
  const float* W_inp = (const float*)d_in[1];
  const float* b_inp = (const float*)d_in[2];
  const float* W_hid = (const float*)d_in[3];
  const float* b_hid = (const float*)d_in[4];
  const float* W_z   = (const float*)d_in[5];
  const float* b_z   = (const float*)d_in[6];
  const float* W_cls = (const float*)d_in[7];
  const float* b_cls = (const float*)d_in[8];

  // workspace: Y (384KB), Z (384KB), flags (2KB), Wz (1.125MB), Wi (768KB)
  unsigned short* Y = (unsigned short*)d_ws;
  unsigned short* Z = Y + SBUF;
  unsigned* flags = (unsigned*)(Z + SBUF);
  unsigned short* Wz = (unsigned short*)(flags + NGRP * 128);
  unsigned short* Wi = Wz + (size_t)WZ_TILES * 512;

  // zero initial state (y0=z0=0) and flags every call
  hipMemsetAsync(d_ws, 0, 2 * SBUF * sizeof(unsigned short) + NGRP * 128 * sizeof(unsigned), stream);

  // convert W_z / W_inp to fragment-ordered bf16 tiles
  conv_w<<<dim3((WZ_TILES + WI_TILES) * 2, 1, 1), dim3(256), 0, stream>>>(W_z, W_inp, Wz, Wi);

  lem_kernel<<<dim3(NBLK), dim3(NTHR), 0, stream>>>(
      x, b_inp, W_hid, b_hid, b_z, W_cls, b_cls,
      (float*)d_out, Y, Z, flags, Wz, Wi);
}

// Round 7
// 2374.799 us; speedup vs baseline: 2.0729x; 1.7704x over previous
//
#include <hip/hip_runtime.h>
#include <stdint.h>

// LEM recurrent net, MI355X persistent-kernel implementation, round 7.
// = Round 4 (best verified: 2.27ms) + rotated chunk order to de-hotspot
// the MALL broadcast: block c starts its K-sweep at chunk pair (c%12) so
// the 48 same-group readers spread across 12 chunk pairs instead of
// hammering one 64B line in lockstep.
// NGRP=4 x CBLK=48 = 192 blocks x 256 thr, 1 block/CU, weights in LDS.
// State: bf16 fragment-ordered [kt][rt][kg][r16][e]; uncached (sc0 sc1)
// dwordx4 loads, 6-batch counted-vmcnt pipeline; plain-store flag barrier.

#define NINP 128
#define NHID 768
#define NOUT 128
#define T_STEPS 256
#define BATCH 256

#define NGRP 4
#define CBLK 48
#define NBLK (NGRP * CBLK)      // 192 blocks
#define NTHR 256
#define KH 24                   // K-chunks of 32 for K=768
#define KI 4                    // K-chunks for K=128

// LDS tile indices (tile = 16 cols x 32 k bf16 = 1KB, fragment-major)
#define T_INP0 72               // after 3*24 W_hid tiles
#define T_WZ0  88               // after 4*4 W_inp tiles
#define NTILES 112              // 112 KB LDS

// state layout [kt:24][rt:16][kg:4][r16:16][e:8] bf16; chunk stride (bf16):
#define CHS 8192                // 16*4*16*8
#define SBUF 196608             // bf16 elements per state buffer (384KB)

typedef short bf16x8 __attribute__((ext_vector_type(8)));
typedef float f32x4 __attribute__((ext_vector_type(4)));
typedef unsigned uint32x4 __attribute__((ext_vector_type(4)));

__device__ __forceinline__ unsigned short f2b(float f) {
  union { float f; unsigned u; } x; x.f = f;
  return (unsigned short)((x.u + 0x7fffu + ((x.u >> 16) & 1u)) >> 16);  // RNE
}
__device__ __forceinline__ float b2f(unsigned short h) {
  union { unsigned u; float f; } x; x.u = ((unsigned)h) << 16; return x.f;
}
__device__ __forceinline__ float fsig(float x) { return 1.0f / (1.0f + __expf(-x)); }
__device__ __forceinline__ float ftanh(float x) {
  float e = __expf(2.0f * x);
  return 1.0f - 2.0f / (e + 1.0f);
}

#define MFMA16(a, b, c) __builtin_amdgcn_mfma_f32_16x16x32_bf16(a, b, c, 0, 0, 0)

#define AL32(p) __hip_atomic_load((const unsigned*)(p), __ATOMIC_RELAXED, __HIP_MEMORY_SCOPE_AGENT)
#define AS32(p, v) __hip_atomic_store((unsigned*)(p), (v), __ATOMIC_RELAXED, __HIP_MEMORY_SCOPE_AGENT)
#define AS16(p, v) __hip_atomic_store((unsigned short*)(p), (v), __ATOMIC_RELAXED, __HIP_MEMORY_SCOPE_AGENT)

// uncached (device-coherent) 16B load; result valid only after s_waitcnt
__device__ __forceinline__ void uld16(uint32x4* dst, const unsigned short* addr) {
  asm volatile("global_load_dwordx4 %0, %1, off sc0 sc1"
               : "=v"(*dst) : "v"(addr));
}
#define WAITV(N) do { \
  asm volatile("s_waitcnt vmcnt(" #N ")" ::: "memory"); \
  __builtin_amdgcn_sched_barrier(0); } while (0)

// fp32 -> hi/lo bf16 fragments (x input, W_cls)
__device__ __forceinline__ void split8(const float* p, bf16x8* hi, bf16x8* lo) {
  union { bf16x8 v; unsigned short s[8]; } H, L;
#pragma unroll
  for (int e = 0; e < 8; ++e) {
    float v = p[e];
    unsigned short h = f2b(v);
    H.s[e] = h;
    L.s[e] = f2b(v - b2f(h));
  }
  *hi = H.v; *lo = L.v;
}

__global__ __launch_bounds__(NTHR, 1) void lem_kernel(
    const float* __restrict__ x,       // [T][B][NINP]
    const float* __restrict__ W_inp,   // [4*NHID][NINP]
    const float* __restrict__ b_inp,   // [4*NHID]
    const float* __restrict__ W_hid,   // [3*NHID][NHID]
    const float* __restrict__ b_hid,   // [3*NHID]
    const float* __restrict__ W_z,     // [NHID][NHID]
    const float* __restrict__ b_z,     // [NHID]
    const float* __restrict__ W_cls,   // [NOUT][NHID]
    const float* __restrict__ b_cls,   // [NOUT]
    float* __restrict__ out,           // [B][NOUT]
    unsigned short* __restrict__ Y,    // bf16 state, fragment-ordered
    unsigned short* __restrict__ Z,
    unsigned* __restrict__ flags)      // per group: flagA[48], pad, flagB[48]
{
  __shared__ unsigned short wlds[NTILES * 512];  // 112 KB

  const int tid = threadIdx.x;
  const int l   = tid & 63;
  const int w   = tid >> 6;            // wave 0..3
  const int g   = blockIdx.x / CBLK;
  const int c   = blockIdx.x % CBLK;
  const int colbase = c * 16;
  const int lc  = l & 15;
  const int kg8 = (l >> 4) * 8;
  const int roff = c % 12;             // per-block chunk-pair rotation

  // ---- one-time: pack weight slices into LDS (bf16, fragment-major) ----
  for (int idx = tid; idx < NTILES * 512; idx += NTHR) {
    int t = idx >> 9;
    int r = idx & 511;
    int ll = r >> 3;
    int e  = r & 7;
    int col16 = ll & 15;
    int kk = ((ll >> 4) * 8) + e;
    float v;
    if (t < T_INP0) {                      // W_hid
      int seg = t / 24, kt = t % 24;
      v = W_hid[(size_t)(seg * NHID + colbase + col16) * NHID + kt * 32 + kk];
    } else if (t < T_WZ0) {                // W_inp
      int u = t - T_INP0; int seg = u >> 2, kt = u & 3;
      v = W_inp[(size_t)(seg * NHID + colbase + col16) * NINP + kt * 32 + kk];
    } else {                               // W_z
      int kt = t - T_WZ0;
      v = W_z[(size_t)(colbase + col16) * NHID + kt * 32 + kk];
    }
    wlds[idx] = f2b(v);
  }
  __syncthreads();

#define LDSB(t) (*(const bf16x8*)&wlds[((t) << 9) + (l << 3)])

  const int col  = colbase + lc;
  const int rt   = 4 * g + w;                   // row tile (16 rows)
  const int rowA = rt * 16 + lc;                // A-fragment row
  const int rowD = rt * 16 + (l >> 4) * 4;      // D rows rowD..rowD+3
  const int rtl  = rt * 512 + (l >> 4) * 128 + lc * 8;  // per-lane load base
  const float c1 = b_inp[col] + b_hid[col];
  const float c2 = b_inp[NHID + col] + b_hid[NHID + col];
  const float cy = b_inp[3 * NHID + col] + b_hid[2 * NHID + col];
  const float cz = b_inp[2 * NHID + col] + b_z[col];
  // store addressing (fragment-ordered, bf16 units)
  const int kts = col >> 5, kgs = (col >> 3) & 3, es = col & 7;
  const int r16b = (l >> 4) * 4;
  unsigned short* zs = Z + ((kts * 16 + rt) * 4 + kgs) * 128 + es;
  unsigned short* ys = Y + ((kts * 16 + rt) * 4 + kgs) * 128 + es;
  unsigned* gfA = flags + g * 128;
  unsigned* gfB = gfA + 64;

  // input projection for step 0 (cached loads; x is read-only)
  f32x4 ai0{0,0,0,0}, ai1{0,0,0,0}, ai2{0,0,0,0}, ai3{0,0,0,0};
  {
    const float* xp0 = x + (size_t)rowA * NINP;
#pragma unroll
    for (int kt = 0; kt < KI; ++kt) {
      bf16x8 ah, al;
      split8(xp0 + kt * 32 + kg8, &ah, &al);
      ai0 = MFMA16(ah, LDSB(T_INP0 + 0 * 4 + kt), ai0);
      ai0 = MFMA16(al, LDSB(T_INP0 + 0 * 4 + kt), ai0);
      ai1 = MFMA16(ah, LDSB(T_INP0 + 1 * 4 + kt), ai1);
      ai1 = MFMA16(al, LDSB(T_INP0 + 1 * 4 + kt), ai1);
      ai2 = MFMA16(ah, LDSB(T_INP0 + 2 * 4 + kt), ai2);
      ai2 = MFMA16(al, LDSB(T_INP0 + 2 * 4 + kt), ai2);
      ai3 = MFMA16(ah, LDSB(T_INP0 + 3 * 4 + kt), ai3);
      ai3 = MFMA16(al, LDSB(T_INP0 + 3 * 4 + kt), ai3);
    }
  }

  f32x4 yloc{0,0,0,0}, zloc{0,0,0,0}, msb{0,0,0,0};

  // 6-deep pipelined slab read, chunk-pair order rotated by roff
#define ISSUE(slot, jj) do { \
    uld16(&bufs[slot][0], pbase + (2 * (jj)) * CHS); \
    uld16(&bufs[slot][1], pbase + (2 * (jj) + 1) * CHS); } while (0)

#define ROT(j) ({ int jr_ = (j) + roff; if (jr_ >= 12) jr_ -= 12; jr_; })

  for (int s = 0; s < T_STEPS; ++s) {
    // ---------- phase A: hid = y @ W_hid^T, z update ----------
    f32x4 h0{0,0,0,0}, h1{0,0,0,0}, h2{0,0,0,0};
    {
      const unsigned short* pbase = Y + rtl;
      uint32x4 bufs[6][2];
      ISSUE(0, ROT(0)); ISSUE(1, ROT(1)); ISSUE(2, ROT(2));
      ISSUE(3, ROT(3)); ISSUE(4, ROT(4));
#pragma unroll
      for (int j = 0; j < 12; ++j) {
        if (j <= 6) { ISSUE((j + 5) % 6, ROT(j + 5)); WAITV(10); }
        else if (j == 7) { WAITV(8); }
        else if (j == 8) { WAITV(6); }
        else if (j == 9) { WAITV(4); }
        else if (j == 10) { WAITV(2); }
        else { WAITV(0); }
        const int sl = j % 6;
        const int jp = ROT(j);              // physical chunk pair
        bf16x8 a0 = __builtin_bit_cast(bf16x8, bufs[sl][0]);
        h0 = MFMA16(a0, LDSB(0 * 24 + 2 * jp), h0);
        h1 = MFMA16(a0, LDSB(1 * 24 + 2 * jp), h1);
        h2 = MFMA16(a0, LDSB(2 * 24 + 2 * jp), h2);
        bf16x8 a1 = __builtin_bit_cast(bf16x8, bufs[sl][1]);
        h0 = MFMA16(a1, LDSB(0 * 24 + 2 * jp + 1), h0);
        h1 = MFMA16(a1, LDSB(1 * 24 + 2 * jp + 1), h1);
        h2 = MFMA16(a1, LDSB(2 * 24 + 2 * jp + 1), h2);
      }
    }
#pragma unroll
    for (int i = 0; i < 4; ++i) {
      float a1 = fsig(ai0[i] + h0[i] + c1);          // ms_dt_bar
      float a2 = fsig(ai1[i] + h1[i] + c2);          // ms_dt
      float gg = ftanh(ai3[i] + h2[i] + cy);
      float zn = (1.0f - a2) * zloc[i] + a2 * gg;
      zloc[i] = zn;
      msb[i] = a1;
      AS16(zs + (r16b + i) * 8, f2b(zn));            // uncached write-through
    }
    __syncthreads();                       // drains vmcnt: stores at MALL
    if (tid == 0) AS32(&gfA[c], (unsigned)(s + 1));

    // overlap barrier latency: input projection for step s+1 (cached)
    f32x4 ni0{0,0,0,0}, ni1{0,0,0,0}, ni2{0,0,0,0}, ni3{0,0,0,0};
    if (s + 1 < T_STEPS) {
      const float* xp = x + ((size_t)(s + 1) * BATCH + rowA) * NINP;
#pragma unroll
      for (int kt = 0; kt < KI; ++kt) {
        bf16x8 ah, al;
        split8(xp + kt * 32 + kg8, &ah, &al);
        ni0 = MFMA16(ah, LDSB(T_INP0 + 0 * 4 + kt), ni0);
        ni0 = MFMA16(al, LDSB(T_INP0 + 0 * 4 + kt), ni0);
        ni1 = MFMA16(ah, LDSB(T_INP0 + 1 * 4 + kt), ni1);
        ni1 = MFMA16(al, LDSB(T_INP0 + 1 * 4 + kt), ni1);
        ni2 = MFMA16(ah, LDSB(T_INP0 + 2 * 4 + kt), ni2);
        ni2 = MFMA16(al, LDSB(T_INP0 + 2 * 4 + kt), ni2);
        ni3 = MFMA16(ah, LDSB(T_INP0 + 3 * 4 + kt), ni3);
        ni3 = MFMA16(al, LDSB(T_INP0 + 3 * 4 + kt), ni3);
      }
    }
    // wait A: all 48 flagA >= s+1 (one coalesced 192B load per poll)
    if (w == 0) {
      const unsigned* fp = gfA + (l < CBLK ? l : 0);
      while (true) {
        unsigned v = AL32(fp);
        if (__all((l >= CBLK) || (v >= (unsigned)(s + 1)))) break;
        __builtin_amdgcn_s_sleep(1);
      }
    }
    __syncthreads();

    // ---------- phase B: zWz = z @ W_z^T, y update ----------
    f32x4 az0{0,0,0,0}, az1{0,0,0,0};
    {
      const unsigned short* pbase = Z + rtl;
      uint32x4 bufs[6][2];
      ISSUE(0, ROT(0)); ISSUE(1, ROT(1)); ISSUE(2, ROT(2));
      ISSUE(3, ROT(3)); ISSUE(4, ROT(4));
#pragma unroll
      for (int j = 0; j < 12; ++j) {
        if (j <= 6) { ISSUE((j + 5) % 6, ROT(j + 5)); WAITV(10); }
        else if (j == 7) { WAITV(8); }
        else if (j == 8) { WAITV(6); }
        else if (j == 9) { WAITV(4); }
        else if (j == 10) { WAITV(2); }
        else { WAITV(0); }
        const int sl = j % 6;
        const int jp = ROT(j);
        bf16x8 a0 = __builtin_bit_cast(bf16x8, bufs[sl][0]);
        az0 = MFMA16(a0, LDSB(T_WZ0 + 2 * jp), az0);
        bf16x8 a1 = __builtin_bit_cast(bf16x8, bufs[sl][1]);
        az1 = MFMA16(a1, LDSB(T_WZ0 + 2 * jp + 1), az1);
      }
    }
#pragma unroll
    for (int i = 0; i < 4; ++i) {
      float tt = ftanh(az0[i] + az1[i] + ai2[i] + cz);
      float yn = (1.0f - msb[i]) * yloc[i] + msb[i] * tt;
      yloc[i] = yn;
      AS16(ys + (r16b + i) * 8, f2b(yn));
    }
    __syncthreads();
    if (tid == 0) AS32(&gfB[c], (unsigned)(s + 1));
    if (w == 0) {
      const unsigned* fp = gfB + (l < CBLK ? l : 0);
      while (true) {
        unsigned v = AL32(fp);
        if (__all((l >= CBLK) || (v >= (unsigned)(s + 1)))) break;
        __builtin_amdgcn_s_sleep(1);
      }
    }
    __syncthreads();

    ai0 = ni0; ai1 = ni1; ai2 = ni2; ai3 = ni3;
  }

  // ---------- epilogue: out = y @ W_cls^T + b_cls (blocks c<8) ----------
  if (c < 8) {
    f32x4 ao0{0,0,0,0}, ao1{0,0,0,0};
    const unsigned short* pbase = Y + rtl;
    for (int kt = 0; kt < KH; kt += 2) {
      uint32x4 q0, q1;
      uld16(&q0, pbase + kt * CHS);
      uld16(&q1, pbase + (kt + 1) * CHS);
      bf16x8 bh0, bl0, bh1, bl1;
      split8(W_cls + (size_t)(colbase + lc) * NHID + kt * 32 + kg8, &bh0, &bl0);
      split8(W_cls + (size_t)(colbase + lc) * NHID + (kt + 1) * 32 + kg8, &bh1, &bl1);
      WAITV(0);
      bf16x8 a0 = __builtin_bit_cast(bf16x8, q0);
      ao0 = MFMA16(a0, bh0, ao0); ao0 = MFMA16(a0, bl0, ao0);
      bf16x8 a1 = __builtin_bit_cast(bf16x8, q1);
      ao1 = MFMA16(a1, bh1, ao1); ao1 = MFMA16(a1, bl1, ao1);
    }
    float bc = b_cls[colbase + lc];
#pragma unroll
    for (int i = 0; i < 4; ++i)
      out[(size_t)(rowD + i) * NOUT + colbase + lc] = ao0[i] + ao1[i] + bc;
  }
}

extern "C" void kernel_launch(void* const* d_in, const int* in_sizes, int n_in,
                              void* d_out, int out_size, void* d_ws, size_t ws_size,
                              hipStream_t stream) {
  (void)in_sizes; (void)n_in; (void)out_size; (void)ws_size;
  const float* x     = (const float*)d_in[0];
  const float* W_inp = (const float*)d_in[1];
  const float* b_inp = (const float*)d_in[2];
  const float* W_hid = (const float*)d_in[3];
  const float* b_hid = (const float*)d_in[4];
  const float* W_z   = (const float*)d_in[5];
  const float* b_z   = (const float*)d_in[6];
  const float* W_cls = (const float*)d_in[7];
  const float* b_cls = (const float*)d_in[8];

  // workspace: Y (384KB), Z (384KB), flags (4 groups * 128 u32 = 2KB)
  unsigned short* Y = (unsigned short*)d_ws;
  unsigned short* Z = Y + SBUF;
  unsigned* flags = (unsigned*)((char*)d_ws + 2 * SBUF * sizeof(unsigned short));

  hipMemsetAsync(d_ws, 0, 2 * SBUF * sizeof(unsigned short) + NGRP * 128 * sizeof(unsigned), stream);

  lem_kernel<<<dim3(NBLK), dim3(NTHR), 0, stream>>>(
      x, W_inp, b_inp, W_hid, b_hid, W_z, b_z, W_cls, b_cls,
      (float*)d_out, Y, Z, flags);
}

// Round 8
// 2114.904 us; speedup vs baseline: 2.3276x; 1.1229x over previous
//
#include <hip/hip_runtime.h>
#include <stdint.h>

// LEM recurrent net, MI355X persistent kernel, round 8.
// CBLK=24 column-blocks (32 cols) x NGRP=8 batch groups (32 rows) = 192
// blocks x 256 thr (4 waves = rt{0,1} x khalf{0,1}), 1 block/CU.
// - State broadcast halved vs R4: traffic ~ CBLK only; waves split K so no
//   duplicate loads; half-K partials pair-reduced via 12KB LDS.
// - W_hid (144KB) in LDS. W_z streamed as cached bf16 frags inside the
//   unified counted-vmcnt pipeline. W_inp frags pinned in registers
//   (step-invariant). x folded into the GEMMs as extra K-chunks (hi/lo),
//   pre-converted once into chunk layout (XF).
// - State: bf16 fragment-ordered [kt][rt][kg][r16][e]; uncached (sc0 sc1)
//   loads/stores; plain-store flag barrier (24 flags/group), wave0 polls.

#define NINP 128
#define NHID 768
#define NOUT 128
#define T_STEPS 256
#define BATCH 256

#define NGRP 8
#define CBLK 24
#define NBLK 192
#define NTHR 256

#define NHTILES 144             // W_hid LDS tiles: [ct:2][seg:3][kt:24]
#define SBUF 196608             // bf16 elems per state buffer (384KB)
#define WZ_ELEMS (1152 * 512)   // W_z tiles  [(c*2+ct)*24+kt][512]
#define WI_ELEMS (768 * 512)    // W_inp tiles [((c*4+seg)*2+ct)*4+xkt][512]
#define XF_ELEMS (256 * 2 * 4 * 16 * 512)  // x chunks [t][hl][xkt][rt][512]

typedef short bf16x8 __attribute__((ext_vector_type(8)));
typedef float f32x4 __attribute__((ext_vector_type(4)));

__device__ __forceinline__ unsigned short f2b(float f) {
  union { float f; unsigned u; } x; x.f = f;
  return (unsigned short)((x.u + 0x7fffu + ((x.u >> 16) & 1u)) >> 16);  // RNE
}
__device__ __forceinline__ float b2f(unsigned short h) {
  union { unsigned u; float f; } x; x.u = ((unsigned)h) << 16; return x.f;
}
__device__ __forceinline__ float fsig(float x) { return 1.0f / (1.0f + __expf(-x)); }
__device__ __forceinline__ float ftanh(float x) {
  float e = __expf(2.0f * x);
  return 1.0f - 2.0f / (e + 1.0f);
}

#define MFMA16(a, b, c) __builtin_amdgcn_mfma_f32_16x16x32_bf16(a, b, c, 0, 0, 0)

#define AL32(p) __hip_atomic_load((const unsigned*)(p), __ATOMIC_RELAXED, __HIP_MEMORY_SCOPE_AGENT)
#define AS32(p, v) __hip_atomic_store((unsigned*)(p), (v), __ATOMIC_RELAXED, __HIP_MEMORY_SCOPE_AGENT)
#define AS16(p, v) __hip_atomic_store((unsigned short*)(p), (v), __ATOMIC_RELAXED, __HIP_MEMORY_SCOPE_AGENT)

// uncached (device-coherent) 16B load -> bf16x8; valid after s_waitcnt
__device__ __forceinline__ void uld16(bf16x8* dst, const unsigned short* addr) {
  asm volatile("global_load_dwordx4 %0, %1, off sc0 sc1" : "=v"(*dst) : "v"(addr));
}
// cached 16B load -> bf16x8 (read-only data), manually counted
__device__ __forceinline__ void cld16(bf16x8* dst, const unsigned short* addr) {
  asm volatile("global_load_dwordx4 %0, %1, off" : "=v"(*dst) : "v"(addr));
}
#define WAITV(N) do { \
  asm volatile("s_waitcnt vmcnt(" #N ")" ::: "memory"); \
  __builtin_amdgcn_sched_barrier(0); } while (0)

// fp32 -> hi/lo bf16 fragments
__device__ __forceinline__ void split8(const float* p, bf16x8* hi, bf16x8* lo) {
  union { bf16x8 v; unsigned short s[8]; } H, L;
#pragma unroll
  for (int e = 0; e < 8; ++e) {
    float v = p[e];
    unsigned short h = f2b(v);
    H.s[e] = h;
    L.s[e] = f2b(v - b2f(h));
  }
  *hi = H.v; *lo = L.v;
}

// ---- prep 1: convert W_z / W_inp to bf16 fragment tiles ----
__global__ __launch_bounds__(256) void conv_w(
    const float* __restrict__ W_z, const float* __restrict__ W_inp,
    unsigned short* __restrict__ Wz, unsigned short* __restrict__ Wi) {
  int idx = blockIdx.x * 256 + threadIdx.x;         // 1920*512 total
  int t = idx >> 9, r = idx & 511;
  int ll = r >> 3, e = r & 7;
  int col16 = ll & 15;
  int kk = ((ll >> 4) * 8) + e;
  if (t < 1152) {                  // W_z: t=(c*2+ct)*24+kt
    int kt = t % 24, ct = (t / 24) & 1, c = t / 48;
    Wz[idx] = f2b(W_z[(size_t)(c * 32 + ct * 16 + col16) * NHID + kt * 32 + kk]);
  } else {                         // W_inp: u=((c*4+seg)*2+ct)*4+xkt
    int u = t - 1152;
    int xkt = u & 3, ct = (u >> 2) & 1, seg = (u >> 3) & 3, c = u >> 5;
    Wi[(size_t)u * 512 + r] =
        f2b(W_inp[(size_t)(seg * NHID + c * 32 + ct * 16 + col16) * NINP + xkt * 32 + kk]);
  }
}

// ---- prep 2: convert x to hi/lo bf16 chunk layout ----
__global__ __launch_bounds__(256) void xprep(
    const float* __restrict__ x, unsigned short* __restrict__ XF) {
  int gid = blockIdx.x * 256 + threadIdx.x;        // 256*4*16*64 total
  int lane = gid & 63;
  int rtx = (gid >> 6) & 15;
  int xkt = (gid >> 10) & 3;
  int t = gid >> 12;
  int kg = lane >> 4, r16 = lane & 15;
  int row = rtx * 16 + r16;
  bf16x8 hi, lo;
  split8(x + ((size_t)t * BATCH + row) * NINP + xkt * 32 + kg * 8, &hi, &lo);
  size_t lo_off = (size_t)kg * 128 + r16 * 8;
  *(bf16x8*)(XF + ((((size_t)t * 2 + 0) * 4 + xkt) * 16 + rtx) * 512 + lo_off) = hi;
  *(bf16x8*)(XF + ((((size_t)t * 2 + 1) * 4 + xkt) * 16 + rtx) * 512 + lo_off) = lo;
}

__global__ __launch_bounds__(NTHR, 1) void lem_kernel(
    const float* __restrict__ b_inp,   // [4*NHID]
    const float* __restrict__ W_hid,   // [3*NHID][NHID]
    const float* __restrict__ b_hid,   // [3*NHID]
    const float* __restrict__ b_z,     // [NHID]
    const float* __restrict__ W_cls,   // [NOUT][NHID]
    const float* __restrict__ b_cls,   // [NOUT]
    float* __restrict__ out,           // [B][NOUT]
    unsigned short* __restrict__ Y,    // bf16 state, chunk layout
    unsigned short* __restrict__ Z,
    unsigned* __restrict__ flags,      // per group: flagA[24]@0, flagB[24]@64
    const unsigned short* __restrict__ Wz,
    const unsigned short* __restrict__ Wi,
    const unsigned short* __restrict__ XF)
{
  __shared__ unsigned short wlds[NHTILES * 512];   // 144 KB
  __shared__ float red[128 * 24];                  // 12 KB reduce buffer

  const int tid = threadIdx.x;
  const int l   = tid & 63;
  const int w   = tid >> 6;              // wave 0..3
  const int rtl = w & 1;                 // row-tile local (0,1)
  const int kh  = w >> 1;                // K-half (0,1)
  const int g   = blockIdx.x / CBLK;
  const int c   = blockIdx.x % CBLK;
  const int colbase = c * 32;
  const int lc  = l & 15;
  const int kg8 = (l >> 4) * 8;
  const int laneoff = (l >> 4) * 128 + lc * 8;
  const int rtg = g * 2 + rtl;           // global row-tile (16 rows)
  const int r16b = (l >> 4) * 4;

  // ---- one-time: pack W_hid slice into LDS: tile=(ct*3+seg)*24+kt ----
  for (int idx = tid; idx < NHTILES * 512; idx += NTHR) {
    int t = idx >> 9;
    int r = idx & 511;
    int ll = r >> 3, e = r & 7;
    int col16 = ll & 15;
    int kk = ((ll >> 4) * 8) + e;
    int kt = t % 24, cs = t / 24;
    int ct = cs / 3, seg = cs % 3;
    wlds[idx] = f2b(W_hid[(size_t)(seg * NHID + colbase + ct * 16 + col16) * NHID + kt * 32 + kk]);
  }

#define LDSB(t) (*(const bf16x8*)&wlds[((t) << 9) + (l << 3)])

  // biases / store pointers per ct
  float c1[2], c2[2], cy[2], cz[2];
  unsigned short *zs[2], *ys[2];
#pragma unroll
  for (int ct = 0; ct < 2; ++ct) {
    int col = colbase + ct * 16 + lc;
    c1[ct] = b_inp[col] + b_hid[col];
    c2[ct] = b_inp[NHID + col] + b_hid[NHID + col];
    cy[ct] = b_inp[3 * NHID + col] + b_hid[2 * NHID + col];
    cz[ct] = b_inp[2 * NHID + col] + b_z[col];
    int kts = col >> 5, kgs = (col >> 3) & 3, es = col & 7;
    zs[ct] = Z + ((kts * 16 + rtg) * 4 + kgs) * 128 + es;
    ys[ct] = Y + ((kts * 16 + rtg) * 4 + kgs) * 128 + es;
  }
  unsigned* gfA = flags + g * 128;
  unsigned* gfB = gfA + 64;
  const int khb = kh * 12;               // this wave's K-half base (kt units)

  // ---- pin step-invariant W_inp fragments in registers ----
  bf16x8 wifA[3][2][2];                  // [hseg][ct][xk2]; hseg2 -> W_inp seg3
  bf16x8 wiB[2][2];                      // seg2 for phase B
#pragma unroll
  for (int hseg = 0; hseg < 3; ++hseg) {
    int wseg = (hseg == 2) ? 3 : hseg;
#pragma unroll
    for (int ct = 0; ct < 2; ++ct)
#pragma unroll
      for (int xk2 = 0; xk2 < 2; ++xk2)
        cld16(&wifA[hseg][ct][xk2],
              Wi + (size_t)((((c * 4 + wseg) * 2 + ct) * 4) + (kh * 2 + xk2)) * 512 + l * 8);
  }
#pragma unroll
  for (int ct = 0; ct < 2; ++ct)
#pragma unroll
    for (int xk2 = 0; xk2 < 2; ++xk2)
      cld16(&wiB[ct][xk2],
            Wi + (size_t)((((c * 4 + 2) * 2 + ct) * 4) + (kh * 2 + xk2)) * 512 + l * 8);

  bf16x8 xa[4];                          // [xk2*2 + hl] for this wave's 2 xkts
#define ISSUE_XA(sidx) do { \
    cld16(&xa[0], XF + ((((size_t)(sidx) * 2 + 0) * 4 + (kh * 2 + 0)) * 16 + rtg) * 512 + laneoff); \
    cld16(&xa[1], XF + ((((size_t)(sidx) * 2 + 1) * 4 + (kh * 2 + 0)) * 16 + rtg) * 512 + laneoff); \
    cld16(&xa[2], XF + ((((size_t)(sidx) * 2 + 0) * 4 + (kh * 2 + 1)) * 16 + rtg) * 512 + laneoff); \
    cld16(&xa[3], XF + ((((size_t)(sidx) * 2 + 1) * 4 + (kh * 2 + 1)) * 16 + rtg) * 512 + laneoff); } while (0)

  ISSUE_XA(0);
  WAITV(0);
  __syncthreads();                       // LDS W_hid ready; all vmem drained

  f32x4 yloc[2], zloc[2], msb[2];
#pragma unroll
  for (int ct = 0; ct < 2; ++ct) { yloc[ct] = f32x4{0,0,0,0}; zloc[ct] = f32x4{0,0,0,0}; }

  float* rp = red + ((size_t)rtl * 64 + l) * 24;   // reduce slot (96B stride)

  bf16x8 ybufs[6][2];
  bf16x8 zbuf[6];
  bf16x8 wzf[6][2];
  const unsigned short* wzb0 = Wz + (size_t)((c * 2 + 0) * 24) * 512 + l * 8;
  const unsigned short* wzb1 = Wz + (size_t)((c * 2 + 1) * 24) * 512 + l * 8;

#define ISSUE_Y(slot, j) do { \
    int kt_ = khb + 2 * (j); \
    uld16(&ybufs[slot][0], Y + (size_t)(kt_ * 16 + rtg) * 512 + laneoff); \
    uld16(&ybufs[slot][1], Y + (size_t)((kt_ + 1) * 16 + rtg) * 512 + laneoff); } while (0)

#define ISSUE_Z(slot, j) do { \
    int kt_ = khb + (j); \
    uld16(&zbuf[slot], Z + (size_t)(kt_ * 16 + rtg) * 512 + laneoff); \
    cld16(&wzf[slot][0], wzb0 + (size_t)kt_ * 512); \
    cld16(&wzf[slot][1], wzb1 + (size_t)kt_ * 512); } while (0)

  for (int s = 0; s < T_STEPS; ++s) {
    // ================= phase A: h = y@W_hid^T + x@W_inp^T (partial K) =====
    f32x4 h[3][2];
#pragma unroll
    for (int sg = 0; sg < 3; ++sg)
#pragma unroll
      for (int ct = 0; ct < 2; ++ct) h[sg][ct] = f32x4{0,0,0,0};

    ISSUE_Y(0, 0); ISSUE_Y(1, 1); ISSUE_Y(2, 2);   // 6 loads out
    WAITV(6);                                       // xa complete (oldest)
    // x-part (registers only)
#pragma unroll
    for (int xk2 = 0; xk2 < 2; ++xk2)
#pragma unroll
      for (int sg = 0; sg < 3; ++sg)
#pragma unroll
        for (int ct = 0; ct < 2; ++ct) {
          h[sg][ct] = MFMA16(xa[xk2 * 2 + 0], wifA[sg][ct][xk2], h[sg][ct]);
          h[sg][ct] = MFMA16(xa[xk2 * 2 + 1], wifA[sg][ct][xk2], h[sg][ct]);
        }
    // y-part: 6 j-units x 2 chunks
#pragma unroll
    for (int j = 0; j < 6; ++j) {
      if (j < 3) ISSUE_Y(j + 3, j + 3);
      if (j < 3) { WAITV(6); } else if (j == 3) { WAITV(4); }
      else if (j == 4) { WAITV(2); } else { WAITV(0); }
#pragma unroll
      for (int i2 = 0; i2 < 2; ++i2) {
        int ktp = khb + 2 * j + i2;
        bf16x8 a = ybufs[j][i2];
#pragma unroll
        for (int ct = 0; ct < 2; ++ct)
#pragma unroll
          for (int sg = 0; sg < 3; ++sg)
            h[sg][ct] = MFMA16(a, LDSB((ct * 3 + sg) * 24 + ktp), h[sg][ct]);
      }
    }
    // pair-reduce K-halves via LDS
    if (kh == 1) {
#pragma unroll
      for (int sg = 0; sg < 3; ++sg)
#pragma unroll
        for (int ct = 0; ct < 2; ++ct)
          *(f32x4*)(rp + (sg * 2 + ct) * 4) = h[sg][ct];
    }
    __syncthreads();
    if (kh == 0) {
#pragma unroll
      for (int sg = 0; sg < 3; ++sg)
#pragma unroll
        for (int ct = 0; ct < 2; ++ct)
          h[sg][ct] += *(const f32x4*)(rp + (sg * 2 + ct) * 4);
#pragma unroll
      for (int ct = 0; ct < 2; ++ct)
#pragma unroll
        for (int i = 0; i < 4; ++i) {
          float a1 = fsig(h[0][ct][i] + c1[ct]);     // ms_dt_bar
          float a2 = fsig(h[1][ct][i] + c2[ct]);     // ms_dt
          float gg = ftanh(h[2][ct][i] + cy[ct]);
          float zn = (1.0f - a2) * zloc[ct][i] + a2 * gg;
          zloc[ct][i] = zn;
          msb[ct][i] = a1;
          AS16(zs[ct] + (r16b + i) * 8, f2b(zn));    // uncached write-through
        }
    }
    __syncthreads();                                  // drain z-stores
    if (tid == 0) AS32(&gfA[c], (unsigned)(s + 1));
    if (w == 0) {
      const unsigned* fp = gfA + (l < CBLK ? l : 0);
      while (true) {
        unsigned v = AL32(fp);
        if (__all((l >= CBLK) || (v >= (unsigned)(s + 1)))) break;
        __builtin_amdgcn_s_sleep(1);
      }
    }
    __syncthreads();

    // ================= phase B: az = z@W_z^T + x@W_inp2^T (partial K) =====
    f32x4 az[2];
    az[0] = f32x4{0,0,0,0}; az[1] = f32x4{0,0,0,0};
    ISSUE_Z(0, 0); ISSUE_Z(1, 1); ISSUE_Z(2, 2); ISSUE_Z(3, 3); ISSUE_Z(4, 4);
    // x-part (registers only; wiB pinned)
#pragma unroll
    for (int xk2 = 0; xk2 < 2; ++xk2)
#pragma unroll
      for (int ct = 0; ct < 2; ++ct) {
        az[ct] = MFMA16(xa[xk2 * 2 + 0], wiB[ct][xk2], az[ct]);
        az[ct] = MFMA16(xa[xk2 * 2 + 1], wiB[ct][xk2], az[ct]);
      }
#pragma unroll
    for (int j = 0; j < 12; ++j) {
      if (j < 7) ISSUE_Z((j + 5) % 6, j + 5);
      if (j < 7) { WAITV(15); } else if (j == 7) { WAITV(12); }
      else if (j == 8) { WAITV(9); } else if (j == 9) { WAITV(6); }
      else if (j == 10) { WAITV(3); } else { WAITV(0); }
      const int sl = j % 6;
      az[0] = MFMA16(zbuf[sl], wzf[sl][0], az[0]);
      az[1] = MFMA16(zbuf[sl], wzf[sl][1], az[1]);
    }
    if (kh == 1) {
      *(f32x4*)(rp + 0) = az[0];
      *(f32x4*)(rp + 4) = az[1];
    }
    __syncthreads();
    if (kh == 0) {
      az[0] += *(const f32x4*)(rp + 0);
      az[1] += *(const f32x4*)(rp + 4);
#pragma unroll
      for (int ct = 0; ct < 2; ++ct)
#pragma unroll
        for (int i = 0; i < 4; ++i) {
          float tt = ftanh(az[ct][i] + cz[ct]);
          float yn = (1.0f - msb[ct][i]) * yloc[ct][i] + msb[ct][i] * tt;
          yloc[ct][i] = yn;
          AS16(ys[ct] + (r16b + i) * 8, f2b(yn));
        }
    }
    __syncthreads();                                  // drain y-stores
    if (tid == 0) AS32(&gfB[c], (unsigned)(s + 1));
    if (s + 1 < T_STEPS) ISSUE_XA(s + 1);             // prefetch next x (read-only)
    if (w == 0) {
      const unsigned* fp = gfB + (l < CBLK ? l : 0);
      while (true) {
        unsigned v = AL32(fp);
        if (__all((l >= CBLK) || (v >= (unsigned)(s + 1)))) break;
        __builtin_amdgcn_s_sleep(1);
      }
    }
    __syncthreads();
  }

  // ======= epilogue: out = y @ W_cls^T + b_cls (blocks c<8, own group) ====
  if (c < 8) {
    const int ocb = c * 16;
    f32x4 ao{0, 0, 0, 0};
    bf16x8 yb[12];
#pragma unroll
    for (int j = 0; j < 12; ++j)
      uld16(&yb[j], Y + (size_t)((khb + j) * 16 + rtg) * 512 + laneoff);
    WAITV(0);
#pragma unroll
    for (int j = 0; j < 12; ++j) {
      int kt = khb + j;
      bf16x8 bh, bl;
      split8(W_cls + (size_t)(ocb + lc) * NHID + kt * 32 + kg8, &bh, &bl);
      ao = MFMA16(yb[j], bh, ao);
      ao = MFMA16(yb[j], bl, ao);
    }
    if (kh == 1) *(f32x4*)(rp + 0) = ao;
    __syncthreads();
    if (kh == 0) {
      ao += *(const f32x4*)(rp + 0);
      float bc = b_cls[ocb + lc];
#pragma unroll
      for (int i = 0; i < 4; ++i)
        out[(size_t)(g * 32 + rtl * 16 + r16b + i) * NOUT + ocb + lc] = ao[i] + bc;
    }
  }
}

extern "C" void kernel_launch(void* const* d_in, const int* in_sizes, int n_in,
                              void* d_out, int out_size, void* d_ws, size_t ws_size,
                              hipStream_t stream) {
  (void)in_sizes; (void)n_in; (void)out_size; (void)ws_size;
  const float* x     = (const float*)d_in[0];
  const float* W_inp = (const float*)d_in[1];
  const float* b_inp = (const float*)d_in[2];
  const float* W_hid = (const float*)d_in[3];
  const float* b_hid = (const float*)d_in[4];
  const float* W_z   = (const float*)d_in[5];
  const float* b_z   = (const float*)d_in[6];
  const float* W_cls = (const float*)d_in[7];
  const float* b_cls = (const float*)d_in[8];

  // ws: Y(384K) Z(384K) flags(4K) Wz(1.13M) Wi(0.77M) XF(33.5M) ~= 36.2 MB
  unsigned short* Y = (unsigned short*)d_ws;
  unsigned short* Z = Y + SBUF;
  unsigned* flags = (unsigned*)(Z + SBUF);
  unsigned short* Wz = (unsigned short*)(flags + NGRP * 128);
  unsigned short* Wi = Wz + WZ_ELEMS;
  unsigned short* XF = Wi + WI_ELEMS;

  // zero state + flags each call
  hipMemsetAsync(d_ws, 0, 2 * SBUF * sizeof(unsigned short) + NGRP * 128 * sizeof(unsigned), stream);

  conv_w<<<dim3(3840), dim3(256), 0, stream>>>(W_z, W_inp, Wz, Wi);
  xprep<<<dim3(4096), dim3(256), 0, stream>>>(x, XF);

  lem_kernel<<<dim3(NBLK), dim3(NTHR), 0, stream>>>(
      b_inp, W_hid, b_hid, b_z, W_cls, b_cls,
      (float*)d_out, Y, Z, flags, Wz, Wi, XF);
}

// Round 11
// 2065.596 us; speedup vs baseline: 2.3832x; 1.0239x over previous
//
#include <hip/hip_runtime.h>
#include <stdint.h>

// LEM recurrent net, MI355X persistent kernel, round 11.
// = Round 8 (verified 2.11ms) + two safe changes:
//   (1) phase-A uncached pipeline deepened: all 6 slots (12 chunk loads)
//       issued up front, counted-vmcnt ladder 12/10/8/6/4/2/0.
//   (2) coalesced state stores: in-wave LDS transpose (zt, 2KB) then one
//       global_store_dwordx4 sc0 sc1 per lane (full 64B granules) instead
//       of 8 scattered 2B stores per thread.
// No vote / no XCC read / no buffer_inv / flags via __hip_atomic (= R8).
// Geometry: NGRP=8 x CBLK=24 = 192 blocks x 256 thr, waves = rtl{0,1} x
// kh{0,1}, 1 block/CU. W_hid in LDS; W_inp pinned in regs; W_z streamed
// cached inside counted pipeline; x folded into GEMMs via prepped XF.
// State: bf16 chunks [kt:24][rt:16][kg:4][r16:16][e:8]; uncached sc0 sc1.

#define NINP 128
#define NHID 768
#define NOUT 128
#define T_STEPS 256
#define BATCH 256

#define NGRP 8
#define CBLK 24
#define NBLK 192
#define NTHR 256

#define NHTILES 144             // W_hid LDS tiles: [ct:2][seg:3][kt:24]
#define SBUF 196608             // bf16 elems per state buffer (384KB)
#define WZ_ELEMS (1152 * 512)
#define WI_ELEMS (768 * 512)

typedef short bf16x8 __attribute__((ext_vector_type(8)));
typedef float f32x4 __attribute__((ext_vector_type(4)));

__device__ __forceinline__ unsigned short f2b(float f) {
  union { float f; unsigned u; } x; x.f = f;
  return (unsigned short)((x.u + 0x7fffu + ((x.u >> 16) & 1u)) >> 16);  // RNE
}
__device__ __forceinline__ float b2f(unsigned short h) {
  union { unsigned u; float f; } x; x.u = ((unsigned)h) << 16; return x.f;
}
__device__ __forceinline__ float fsig(float x) { return 1.0f / (1.0f + __expf(-x)); }
__device__ __forceinline__ float ftanh(float x) {
  float e = __expf(2.0f * x);
  return 1.0f - 2.0f / (e + 1.0f);
}

#define MFMA16(a, b, c) __builtin_amdgcn_mfma_f32_16x16x32_bf16(a, b, c, 0, 0, 0)

#define AL32(p) __hip_atomic_load((const unsigned*)(p), __ATOMIC_RELAXED, __HIP_MEMORY_SCOPE_AGENT)
#define AS32(p, v) __hip_atomic_store((unsigned*)(p), (v), __ATOMIC_RELAXED, __HIP_MEMORY_SCOPE_AGENT)

// uncached (device-coherent) 16B load -> bf16x8; valid after s_waitcnt
__device__ __forceinline__ void uld16(bf16x8* dst, const unsigned short* addr) {
  asm volatile("global_load_dwordx4 %0, %1, off sc0 sc1" : "=v"(*dst) : "v"(addr));
}
// cached 16B load -> bf16x8 (read-only data), manually counted
__device__ __forceinline__ void cld16(bf16x8* dst, const unsigned short* addr) {
  asm volatile("global_load_dwordx4 %0, %1, off" : "=v"(*dst) : "v"(addr));
}
// uncached (device-coherent) 16B store
__device__ __forceinline__ void ust16(unsigned short* addr, bf16x8 v) {
  asm volatile("global_store_dwordx4 %0, %1, off sc0 sc1" :: "v"(addr), "v"(v) : "memory");
}
#define WAITV(N) do { \
  asm volatile("s_waitcnt vmcnt(" #N ")" ::: "memory"); \
  __builtin_amdgcn_sched_barrier(0); } while (0)

__device__ __forceinline__ void split8(const float* p, bf16x8* hi, bf16x8* lo) {
  union { bf16x8 v; unsigned short s[8]; } H, L;
#pragma unroll
  for (int e = 0; e < 8; ++e) {
    float v = p[e];
    unsigned short h = f2b(v);
    H.s[e] = h;
    L.s[e] = f2b(v - b2f(h));
  }
  *hi = H.v; *lo = L.v;
}

// ---- prep 1: convert W_z / W_inp to bf16 fragment tiles ----
__global__ __launch_bounds__(256) void conv_w(
    const float* __restrict__ W_z, const float* __restrict__ W_inp,
    unsigned short* __restrict__ Wz, unsigned short* __restrict__ Wi) {
  int idx = blockIdx.x * 256 + threadIdx.x;
  int t = idx >> 9, r = idx & 511;
  int ll = r >> 3, e = r & 7;
  int col16 = ll & 15;
  int kk = ((ll >> 4) * 8) + e;
  if (t < 1152) {
    int kt = t % 24, ct = (t / 24) & 1, c = t / 48;
    Wz[idx] = f2b(W_z[(size_t)(c * 32 + ct * 16 + col16) * NHID + kt * 32 + kk]);
  } else {
    int u = t - 1152;
    int xkt = u & 3, ct = (u >> 2) & 1, seg = (u >> 3) & 3, c = u >> 5;
    Wi[(size_t)u * 512 + r] =
        f2b(W_inp[(size_t)(seg * NHID + c * 32 + ct * 16 + col16) * NINP + xkt * 32 + kk]);
  }
}

// ---- prep 2: convert x to hi/lo bf16 chunk layout ----
__global__ __launch_bounds__(256) void xprep(
    const float* __restrict__ x, unsigned short* __restrict__ XF) {
  int gid = blockIdx.x * 256 + threadIdx.x;
  int lane = gid & 63;
  int rtx = (gid >> 6) & 15;
  int xkt = (gid >> 10) & 3;
  int t = gid >> 12;
  int kg = lane >> 4, r16 = lane & 15;
  int row = rtx * 16 + r16;
  bf16x8 hi, lo;
  split8(x + ((size_t)t * BATCH + row) * NINP + xkt * 32 + kg * 8, &hi, &lo);
  size_t lo_off = (size_t)kg * 128 + r16 * 8;
  *(bf16x8*)(XF + ((((size_t)t * 2 + 0) * 4 + xkt) * 16 + rtx) * 512 + lo_off) = hi;
  *(bf16x8*)(XF + ((((size_t)t * 2 + 1) * 4 + xkt) * 16 + rtx) * 512 + lo_off) = lo;
}

__global__ __launch_bounds__(NTHR, 1) void lem_kernel(
    const float* __restrict__ b_inp,   // [4*NHID]
    const float* __restrict__ W_hid,   // [3*NHID][NHID]
    const float* __restrict__ b_hid,   // [3*NHID]
    const float* __restrict__ b_z,     // [NHID]
    const float* __restrict__ W_cls,   // [NOUT][NHID]
    const float* __restrict__ b_cls,   // [NOUT]
    float* __restrict__ out,           // [B][NOUT]
    unsigned short* __restrict__ Y,    // bf16 state, chunk layout
    unsigned short* __restrict__ Z,
    unsigned* __restrict__ flags,      // per group: flagA[24]@0, flagB[24]@64
    const unsigned short* __restrict__ Wz,
    const unsigned short* __restrict__ Wi,
    const unsigned short* __restrict__ XF)
{
  __shared__ unsigned short wlds[NHTILES * 512];   // 144 KB
  __shared__ float red[128 * 24];                  // 12 KB reduce buffer
  __shared__ unsigned short zt[2 * 512];           // 2 KB transpose tiles

  const int tid = threadIdx.x;
  const int l   = tid & 63;
  const int w   = tid >> 6;              // wave 0..3
  const int rtl = w & 1;                 // row-tile local (0,1)
  const int kh  = w >> 1;                // K-half (0,1)
  const int g   = blockIdx.x / CBLK;
  const int c   = blockIdx.x % CBLK;
  const int colbase = c * 32;
  const int lc  = l & 15;
  const int kg8 = (l >> 4) * 8;
  const int laneoff = (l >> 4) * 128 + lc * 8;
  const int rtg = g * 2 + rtl;           // global row-tile (16 rows)
  const int r16b = (l >> 4) * 4;

  // ---- one-time: pack W_hid slice into LDS: tile=(ct*3+seg)*24+kt ----
  for (int idx = tid; idx < NHTILES * 512; idx += NTHR) {
    int t = idx >> 9;
    int r = idx & 511;
    int ll = r >> 3, e = r & 7;
    int col16 = ll & 15;
    int kk = ((ll >> 4) * 8) + e;
    int kt = t % 24, cs = t / 24;
    int ct = cs / 3, seg = cs % 3;
    wlds[idx] = f2b(W_hid[(size_t)(seg * NHID + colbase + ct * 16 + col16) * NHID + kt * 32 + kk]);
  }

#define LDSB(t) (*(const bf16x8*)&wlds[((t) << 9) + (l << 3)])

  // biases per ct
  float c1[2], c2[2], cy[2], cz[2];
#pragma unroll
  for (int ct = 0; ct < 2; ++ct) {
    int col = colbase + ct * 16 + lc;
    c1[ct] = b_inp[col] + b_hid[col];
    c2[ct] = b_inp[NHID + col] + b_hid[NHID + col];
    cy[ct] = b_inp[3 * NHID + col] + b_hid[2 * NHID + col];
    cz[ct] = b_inp[2 * NHID + col] + b_z[col];
  }
  unsigned* gfA = flags + g * 128;
  unsigned* gfB = gfA + 64;
  const int khb = kh * 12;               // this wave's K-half base (kt units)
  // coalesced store chunk bases (block c's 32 cols == chunk kt=c)
  unsigned short* Zc = Z + (size_t)(c * 16 + rtg) * 512;
  unsigned short* Yc = Y + (size_t)(c * 16 + rtg) * 512;

  // ---- pin step-invariant W_inp fragments in registers ----
  bf16x8 wifA[3][2][2];                  // [hseg][ct][xk2]; hseg2 -> W_inp seg3
  bf16x8 wiB[2][2];                      // seg2 for phase B
#pragma unroll
  for (int hseg = 0; hseg < 3; ++hseg) {
    int wseg = (hseg == 2) ? 3 : hseg;
#pragma unroll
    for (int ct = 0; ct < 2; ++ct)
#pragma unroll
      for (int xk2 = 0; xk2 < 2; ++xk2)
        cld16(&wifA[hseg][ct][xk2],
              Wi + (size_t)((((c * 4 + wseg) * 2 + ct) * 4) + (kh * 2 + xk2)) * 512 + l * 8);
  }
#pragma unroll
  for (int ct = 0; ct < 2; ++ct)
#pragma unroll
    for (int xk2 = 0; xk2 < 2; ++xk2)
      cld16(&wiB[ct][xk2],
            Wi + (size_t)((((c * 4 + 2) * 2 + ct) * 4) + (kh * 2 + xk2)) * 512 + l * 8);

  bf16x8 xa[4];                          // [xk2*2 + hl] for this wave's 2 xkts
#define ISSUE_XA(sidx) do { \
    cld16(&xa[0], XF + ((((size_t)(sidx) * 2 + 0) * 4 + (kh * 2 + 0)) * 16 + rtg) * 512 + laneoff); \
    cld16(&xa[1], XF + ((((size_t)(sidx) * 2 + 1) * 4 + (kh * 2 + 0)) * 16 + rtg) * 512 + laneoff); \
    cld16(&xa[2], XF + ((((size_t)(sidx) * 2 + 0) * 4 + (kh * 2 + 1)) * 16 + rtg) * 512 + laneoff); \
    cld16(&xa[3], XF + ((((size_t)(sidx) * 2 + 1) * 4 + (kh * 2 + 1)) * 16 + rtg) * 512 + laneoff); } while (0)

  ISSUE_XA(0);
  WAITV(0);
  __syncthreads();                       // LDS W_hid ready; all vmem drained

  f32x4 yloc[2], zloc[2], msb[2];
#pragma unroll
  for (int ct = 0; ct < 2; ++ct) { yloc[ct] = f32x4{0,0,0,0}; zloc[ct] = f32x4{0,0,0,0}; }

  float* rp = red + (rtl * 64 + l) * 24;           // 96B stride, 16B aligned
  unsigned short* trow = zt + rtl * 512;           // kh==0 waves only

  bf16x8 ybufs[6][2];
  bf16x8 zbuf[6];
  bf16x8 wzf[6][2];
  const unsigned short* wzb0 = Wz + (size_t)((c * 2 + 0) * 24) * 512 + l * 8;
  const unsigned short* wzb1 = Wz + (size_t)((c * 2 + 1) * 24) * 512 + l * 8;

#define ISSUE_Y(slot, j) do { \
    int kt_ = khb + 2 * (j); \
    uld16(&ybufs[slot][0], Y + (size_t)(kt_ * 16 + rtg) * 512 + laneoff); \
    uld16(&ybufs[slot][1], Y + (size_t)((kt_ + 1) * 16 + rtg) * 512 + laneoff); } while (0)

#define ISSUE_Z(slot, j) do { \
    int kt_ = khb + (j); \
    uld16(&zbuf[slot], Z + (size_t)(kt_ * 16 + rtg) * 512 + laneoff); \
    cld16(&wzf[slot][0], wzb0 + (size_t)kt_ * 512); \
    cld16(&wzf[slot][1], wzb1 + (size_t)kt_ * 512); } while (0)

  for (int s = 0; s < T_STEPS; ++s) {
    // ===== phase A: h = y@W_hid^T + x@W_inp^T (partial K per wave) =====
    f32x4 h[3][2];
#pragma unroll
    for (int sg = 0; sg < 3; ++sg)
#pragma unroll
      for (int ct = 0; ct < 2; ++ct) h[sg][ct] = f32x4{0,0,0,0};

    // deep pipeline: all 12 uncached chunk loads in flight
    ISSUE_Y(0, 0); ISSUE_Y(1, 1); ISSUE_Y(2, 2);
    ISSUE_Y(3, 3); ISSUE_Y(4, 4); ISSUE_Y(5, 5);
    WAITV(12);                                      // xa (older) complete
#pragma unroll
    for (int xk2 = 0; xk2 < 2; ++xk2)
#pragma unroll
      for (int sg = 0; sg < 3; ++sg)
#pragma unroll
        for (int ct = 0; ct < 2; ++ct) {
          h[sg][ct] = MFMA16(xa[xk2 * 2 + 0], wifA[sg][ct][xk2], h[sg][ct]);
          h[sg][ct] = MFMA16(xa[xk2 * 2 + 1], wifA[sg][ct][xk2], h[sg][ct]);
        }
#pragma unroll
    for (int j = 0; j < 6; ++j) {
      if (j == 0) { WAITV(10); } else if (j == 1) { WAITV(8); }
      else if (j == 2) { WAITV(6); } else if (j == 3) { WAITV(4); }
      else if (j == 4) { WAITV(2); } else { WAITV(0); }
#pragma unroll
      for (int i2 = 0; i2 < 2; ++i2) {
        int ktp = khb + 2 * j + i2;
        bf16x8 a = ybufs[j][i2];
#pragma unroll
        for (int ct = 0; ct < 2; ++ct)
#pragma unroll
          for (int sg = 0; sg < 3; ++sg)
            h[sg][ct] = MFMA16(a, LDSB((ct * 3 + sg) * 24 + ktp), h[sg][ct]);
      }
    }
    if (kh == 1) {
#pragma unroll
      for (int sg = 0; sg < 3; ++sg)
#pragma unroll
        for (int ct = 0; ct < 2; ++ct)
          *(f32x4*)(rp + (sg * 2 + ct) * 4) = h[sg][ct];
    }
    __syncthreads();
    if (kh == 0) {
#pragma unroll
      for (int sg = 0; sg < 3; ++sg)
#pragma unroll
        for (int ct = 0; ct < 2; ++ct)
          h[sg][ct] += *(const f32x4*)(rp + (sg * 2 + ct) * 4);
#pragma unroll
      for (int ct = 0; ct < 2; ++ct)
#pragma unroll
        for (int i = 0; i < 4; ++i) {
          float a1 = fsig(h[0][ct][i] + c1[ct]);     // ms_dt_bar
          float a2 = fsig(h[1][ct][i] + c2[ct]);     // ms_dt
          float gg = ftanh(h[2][ct][i] + cy[ct]);
          float zn = (1.0f - a2) * zloc[ct][i] + a2 * gg;
          zloc[ct][i] = zn;
          msb[ct][i] = a1;
          int jj = ct * 16 + lc;
          trow[((jj >> 3) * 16 + r16b + i) * 8 + (jj & 7)] = f2b(zn);
        }
      asm volatile("s_waitcnt lgkmcnt(0)" ::: "memory");
      __builtin_amdgcn_sched_barrier(0);
      bf16x8 zrun = *(const bf16x8*)(trow + l * 8);
      ust16(Zc + l * 8, zrun);                       // coalesced 1KB/wave
    }
    __syncthreads();                                  // drain z-stores
    if (tid == 0) AS32(&gfA[c], (unsigned)(s + 1));
    if (w == 0) {
      const unsigned* fp = gfA + (l < CBLK ? l : 0);
      while (true) {
        unsigned v = AL32(fp);
        if (__all((l >= CBLK) || (v >= (unsigned)(s + 1)))) break;
        __builtin_amdgcn_s_sleep(1);
      }
    }
    __syncthreads();

    // ===== phase B: az = z@W_z^T + x@W_inp2^T (partial K per wave) =====
    f32x4 az[2];
    az[0] = f32x4{0,0,0,0}; az[1] = f32x4{0,0,0,0};
    ISSUE_Z(0, 0); ISSUE_Z(1, 1); ISSUE_Z(2, 2); ISSUE_Z(3, 3); ISSUE_Z(4, 4);
#pragma unroll
    for (int xk2 = 0; xk2 < 2; ++xk2)
#pragma unroll
      for (int ct = 0; ct < 2; ++ct) {
        az[ct] = MFMA16(xa[xk2 * 2 + 0], wiB[ct][xk2], az[ct]);
        az[ct] = MFMA16(xa[xk2 * 2 + 1], wiB[ct][xk2], az[ct]);
      }
#pragma unroll
    for (int j = 0; j < 12; ++j) {
      if (j < 7) ISSUE_Z((j + 5) % 6, j + 5);
      if (j < 7) { WAITV(15); } else if (j == 7) { WAITV(12); }
      else if (j == 8) { WAITV(9); } else if (j == 9) { WAITV(6); }
      else if (j == 10) { WAITV(3); } else { WAITV(0); }
      const int sl = j % 6;
      az[0] = MFMA16(zbuf[sl], wzf[sl][0], az[0]);
      az[1] = MFMA16(zbuf[sl], wzf[sl][1], az[1]);
    }
    if (kh == 1) {
      *(f32x4*)(rp + 0) = az[0];
      *(f32x4*)(rp + 4) = az[1];
    }
    __syncthreads();
    if (kh == 0) {
      az[0] += *(const f32x4*)(rp + 0);
      az[1] += *(const f32x4*)(rp + 4);
#pragma unroll
      for (int ct = 0; ct < 2; ++ct)
#pragma unroll
        for (int i = 0; i < 4; ++i) {
          float tt = ftanh(az[ct][i] + cz[ct]);
          float yn = (1.0f - msb[ct][i]) * yloc[ct][i] + msb[ct][i] * tt;
          yloc[ct][i] = yn;
          int jj = ct * 16 + lc;
          trow[((jj >> 3) * 16 + r16b + i) * 8 + (jj & 7)] = f2b(yn);
        }
      asm volatile("s_waitcnt lgkmcnt(0)" ::: "memory");
      __builtin_amdgcn_sched_barrier(0);
      bf16x8 yrun = *(const bf16x8*)(trow + l * 8);
      ust16(Yc + l * 8, yrun);
    }
    __syncthreads();                                  // drain y-stores
    if (tid == 0) AS32(&gfB[c], (unsigned)(s + 1));
    if (s + 1 < T_STEPS) ISSUE_XA(s + 1);             // prefetch next x
    if (w == 0) {
      const unsigned* fp = gfB + (l < CBLK ? l : 0);
      while (true) {
        unsigned v = AL32(fp);
        if (__all((l >= CBLK) || (v >= (unsigned)(s + 1)))) break;
        __builtin_amdgcn_s_sleep(1);
      }
    }
    __syncthreads();
  }

  // ======= epilogue: out = y @ W_cls^T + b_cls (blocks c<8, own group) ====
  if (c < 8) {
    const int ocb = c * 16;
    f32x4 ao{0, 0, 0, 0};
    bf16x8 yb[12];
#pragma unroll
    for (int j = 0; j < 12; ++j)
      uld16(&yb[j], Y + (size_t)((khb + j) * 16 + rtg) * 512 + laneoff);
    WAITV(0);
#pragma unroll
    for (int j = 0; j < 12; ++j) {
      int kt = khb + j;
      bf16x8 bh, bl;
      split8(W_cls + (size_t)(ocb + lc) * NHID + kt * 32 + kg8, &bh, &bl);
      ao = MFMA16(yb[j], bh, ao);
      ao = MFMA16(yb[j], bl, ao);
    }
    if (kh == 1) *(f32x4*)(rp + 0) = ao;
    __syncthreads();
    if (kh == 0) {
      ao += *(const f32x4*)(rp + 0);
      float bc = b_cls[ocb + lc];
#pragma unroll
      for (int i = 0; i < 4; ++i)
        out[(size_t)(g * 32 + rtl * 16 + r16b + i) * NOUT + ocb + lc] = ao[i] + bc;
    }
  }
}

extern "C" void kernel_launch(void* const* d_in, const int* in_sizes, int n_in,
                              void* d_out, int out_size, void* d_ws, size_t ws_size,
                              hipStream_t stream) {
  (void)in_sizes; (void)n_in; (void)out_size; (void)ws_size;
  const float* x     = (const float*)d_in[0];
  const float* W_inp = (const float*)d_in[1];
  const float* b_inp = (const float*)d_in[2];
  const float* W_hid = (const float*)d_in[3];
  const float* b_hid = (const float*)d_in[4];
  const float* W_z   = (const float*)d_in[5];
  const float* b_z   = (const float*)d_in[6];
  const float* W_cls = (const float*)d_in[7];
  const float* b_cls = (const float*)d_in[8];

  // ws: Y(384K) Z(384K) flags(4K) Wz(1.13M) Wi(0.77M) XF(33.5M) ~= 36.2 MB
  unsigned short* Y = (unsigned short*)d_ws;
  unsigned short* Z = Y + SBUF;
  unsigned* flags = (unsigned*)(Z + SBUF);
  unsigned short* Wz = (unsigned short*)(flags + NGRP * 128);
  unsigned short* Wi = Wz + WZ_ELEMS;
  unsigned short* XF = Wi + WI_ELEMS;

  // zero state + flags each call
  hipMemsetAsync(d_ws, 0, 2 * SBUF * sizeof(unsigned short) + NGRP * 128 * sizeof(unsigned), stream);

  conv_w<<<dim3(3840), dim3(256), 0, stream>>>(W_z, W_inp, Wz, Wi);
  xprep<<<dim3(4096), dim3(256), 0, stream>>>(x, XF);

  lem_kernel<<<dim3(NBLK), dim3(NTHR), 0, stream>>>(
      b_inp, W_hid, b_hid, b_z, W_cls, b_cls,
      (float*)d_out, Y, Z, flags, Wz, Wi, XF);
}